// Round 11
// baseline (2342.525 us; speedup 1.0000x reference)
//
#include <hip/hip_runtime.h>
#include <math.h>

#define NC 8
#define NDIM 32
#define LDSD 34            // stride 34: rows 8B-aligned (float2); col access 2-way bank alias (free)
#define MAT (NDIM * LDSD)  // 1088 floats per LDS matrix
#define EV_EPS 1e-10f
#define NPART 64

#if __has_builtin(__builtin_amdgcn_rcpf)
__device__ inline float fast_rcp(float x) { return __builtin_amdgcn_rcpf(x); }
#else
__device__ inline float fast_rcp(float x) { return 1.f / x; }
#endif
#if __has_builtin(__builtin_amdgcn_rsqf)
__device__ inline float fast_rsq(float x) { return __builtin_amdgcn_rsqf(x); }
#else
__device__ inline float fast_rsq(float x) { return 1.f / sqrtf(x); }
#endif

// ---------- 32x32 LDS helpers ----------
template <int NT>
__device__ inline void g2l(const float* g, float* l, int t) {
    for (int idx2 = t; idx2 < 512; idx2 += NT) {
        int i = idx2 >> 4, jp = idx2 & 15;
        *(float2*)&l[i * LDSD + 2 * jp] = *(const float2*)&g[i * 32 + 2 * jp];
    }
}

// ---------- register-tiled LDS matmuls (one wave; 8-row x 2-col tile/lane; t = 0..63) ----------
// C = A * B.  Wave-private safe for ANY aliasing (C==A or C==B): all 160 read
// instructions precede all 8 stores in the wave's in-order instruction stream,
// and the compiler cannot reorder may-aliasing LDS accesses.
__device__ inline void mmb_nn(const float* A, const float* B, float* C, int t) {
    int j2 = (t & 15) * 2;
    int i0 = (t >> 4) * 8;
    float2 ac[8];
#pragma unroll
    for (int r = 0; r < 8; ++r) { ac[r].x = 0.f; ac[r].y = 0.f; }
#pragma unroll
    for (int k = 0; k < 32; k += 2) {
        float2 b0 = *(const float2*)&B[k * LDSD + j2];
        float2 b1 = *(const float2*)&B[(k + 1) * LDSD + j2];
#pragma unroll
        for (int r = 0; r < 8; ++r) {
            float2 a = *(const float2*)&A[(i0 + r) * LDSD + k];
            ac[r].x = fmaf(a.x, b0.x, fmaf(a.y, b1.x, ac[r].x));
            ac[r].y = fmaf(a.x, b0.y, fmaf(a.y, b1.y, ac[r].y));
        }
    }
#pragma unroll
    for (int r = 0; r < 8; ++r) *(float2*)&C[(i0 + r) * LDSD + j2] = ac[r];
}
// gC(global, stride 32) = A * B^T
__device__ inline void mmb_nt_g(const float* A, const float* B, float* gC, int t) {
    int j2 = (t & 15) * 2;
    int i0 = (t >> 4) * 8;
    float2 ac[8];
#pragma unroll
    for (int r = 0; r < 8; ++r) { ac[r].x = 0.f; ac[r].y = 0.f; }
#pragma unroll
    for (int l = 0; l < 32; l += 2) {
        float2 b0 = *(const float2*)&B[j2 * LDSD + l];
        float2 b1 = *(const float2*)&B[(j2 + 1) * LDSD + l];
#pragma unroll
        for (int r = 0; r < 8; ++r) {
            float2 a = *(const float2*)&A[(i0 + r) * LDSD + l];
            ac[r].x = fmaf(a.x, b0.x, fmaf(a.y, b0.y, ac[r].x));
            ac[r].y = fmaf(a.x, b1.x, fmaf(a.y, b1.y, ac[r].y));
        }
    }
#pragma unroll
    for (int r = 0; r < 8; ++r) *(float2*)&gC[(i0 + r) * 32 + j2] = ac[r];
}

// ---------- register-resident XOR-ordered Jacobi, eigenvalues only, fixed sweeps ----------
// Lane lh holds column lh skewed: m_[r] = M[r^lh][lh]; diag = m_[0].
__device__ inline void rjacobi_fixed(float* m_, int nsweep) {
    for (int sweep = 0; sweep < nsweep; ++sweep) {
#pragma unroll
        for (int mm = 1; mm < 32; ++mm) {
            float app = m_[0];
            float aqq = __shfl_xor(app, mm, 32);
            float apq = m_[mm];
            float apqc = __builtin_copysignf(fmaxf(fabsf(apq), 1e-36f), apq);
            float tau = (aqq - app) * 0.5f * fast_rcp(apqc);
            float den = fabsf(tau) + sqrtf(fmaf(tau, tau, 1.f));
            float t = __builtin_copysignf(fast_rcp(den), tau);
            t = (fabsf(apq) > 1e-36f) ? t : 0.f;
            float cc = fast_rsq(fmaf(t, t, 1.f));
            float ss = t * cc;
#pragma unroll
            for (int r = 0; r < 32; ++r) {
                if (r < (r ^ mm)) {
                    const int r2 = r ^ mm;
                    float ti = __shfl_xor(t, r, 32);
                    float ci = fast_rsq(fmaf(ti, ti, 1.f));
                    float si = ti * ci;
                    float x = m_[r], y = m_[r2];
                    m_[r]  = ci * x - si * y;
                    m_[r2] = ci * y + si * x;
                }
            }
            float o[32];
#pragma unroll
            for (int u = 0; u < 32; ++u) o[u] = __shfl_xor(m_[u ^ mm], mm, 32);
#pragma unroll
            for (int u = 0; u < 32; ++u) m_[u] = fmaf(cc, m_[u], -ss * o[u]);
        }
    }
}

// ---------- split-role register Jacobi: half 0 solves M, half 1 accumulates W·V ----------
template <int NSWEEP>
__device__ inline void rjacobi_split(float* z_, int half, int lh) {
    for (int sweep = 0; sweep < NSWEEP; ++sweep) {
#pragma unroll
        for (int mm = 1; mm < 32; ++mm) {
            float app = z_[0];
            float aqq = __shfl_xor(app, mm, 32);
            float apq = z_[mm];
            float apqc = __builtin_copysignf(fmaxf(fabsf(apq), 1e-36f), apq);
            float tau = (aqq - app) * 0.5f * fast_rcp(apqc);
            float den = fabsf(tau) + sqrtf(fmaf(tau, tau, 1.f));
            float t = __builtin_copysignf(fast_rcp(den), tau);
            t = (fabsf(apq) > 1e-36f) ? t : 0.f;
            t = __shfl(t, lh, 64);               // half 1 inherits half 0's t (wave-local)
            float cc = fast_rsq(fmaf(t, t, 1.f));
            float ss = t * cc;
            if (half == 0) {                     // row rotations on M only (t-refetch)
#pragma unroll
                for (int r = 0; r < 32; ++r) {
                    if (r < (r ^ mm)) {
                        const int r2 = r ^ mm;
                        float ti = __shfl_xor(t, r, 32);
                        float ci = fast_rsq(fmaf(ti, ti, 1.f));
                        float si = ti * ci;
                        float x = z_[r], y = z_[r2];
                        z_[r]  = ci * x - si * y;
                        z_[r2] = ci * y + si * x;
                    }
                }
            }
            float o[32];
#pragma unroll
            for (int u = 0; u < 32; ++u) o[u] = __shfl_xor(z_[u ^ mm], mm, 32);
#pragma unroll
            for (int u = 0; u < 32; ++u) z_[u] = fmaf(cc, z_[u], -ss * o[u]);
        }
    }
}

// ---------- kernels ----------
__global__ void __launch_bounds__(256) k_accum_part(const float* src, const int* labels, int B, float* part) {
    int blk = blockIdx.x, tid = threadIdx.x;
    int chunk = (B + NPART - 1) / NPART;
    int b0 = blk * chunk, b1 = b0 + chunk < B ? b0 + chunk : B;
    float acc[NC][4];
#pragma unroll
    for (int c = 0; c < NC; ++c)
#pragma unroll
        for (int e = 0; e < 4; ++e) acc[c][e] = 0.f;
    for (int b = b0; b < b1; ++b) {
        int lb = labels[b];
        float x[4];
#pragma unroll
        for (int e = 0; e < 4; ++e) x[e] = src[b * 1024 + tid + 256 * e];
#pragma unroll
        for (int c = 0; c < NC; ++c) {
            if (lb == c) {
#pragma unroll
                for (int e = 0; e < 4; ++e) acc[c][e] += x[e];
            }
        }
    }
#pragma unroll
    for (int c = 0; c < NC; ++c)
#pragma unroll
        for (int e = 0; e < 4; ++e) part[(blk * NC + c) * 1024 + tid + 256 * e] = acc[c][e];
}

// fused: reduce partials -> bary0 (global + LDS tile) -> wave-0 eigen -> sqrtm/invsqrtm
__global__ void __launch_bounds__(256) k_bary0_eig(const float* part, const int* labels, int B,
                                                   float* bary0, float* sqrtm, float* invsqrtm) {
    __shared__ __align__(16) float P[MAT], Q[MAT];
    __shared__ int sc[4];
    int c = blockIdx.x, tid = threadIdx.x;
    int cnt = 0;
    for (int b = tid; b < B; b += 256) cnt += (labels[b] == c) ? 1 : 0;
#pragma unroll
    for (int off = 32; off > 0; off >>= 1) cnt += __shfl_down(cnt, off);
    if ((tid & 63) == 0) sc[tid >> 6] = cnt;
    __syncthreads();
    int total = sc[0] + sc[1] + sc[2] + sc[3];
    float acc[4] = {0.f, 0.f, 0.f, 0.f};
    for (int k = 0; k < NPART; ++k) {
#pragma unroll
        for (int e = 0; e < 4; ++e) acc[e] += part[(k * NC + c) * 1024 + tid + 256 * e];
    }
    float inv = 1.f / (float)total;
#pragma unroll
    for (int e = 0; e < 4; ++e) {
        int idx = tid + 256 * e;
        float v = acc[e] * inv;
        P[(idx >> 5) * LDSD + (idx & 31)] = v;
        bary0[c * 1024 + idx] = v;
    }
    __syncthreads();
    if (tid < 64) {
        int half = tid >> 5, lh = tid & 31;
        float z_[32];
        if (half == 0) {
#pragma unroll
            for (int r = 0; r < 32; ++r) {
                int i = r ^ lh;
                z_[r] = 0.5f * (P[i * LDSD + lh] + P[lh * LDSD + i]);
            }
        } else {
#pragma unroll
            for (int r = 0; r < 32; ++r) z_[r] = (r == 0) ? 1.f : 0.f;   // V0 = I col
        }
        rjacobi_split<5>(z_, half, lh);
        float lam = __shfl(z_[0], lh, 64);
        float esq = sqrtf(fmaxf(lam, 0.f));
        float eisq = fast_rsq(fmaxf(lam, 1e-30f));
        if (half == 1) {
#pragma unroll
            for (int r = 0; r < 32; ++r) {
                int i = r ^ lh;
                Q[i * LDSD + lh] = z_[r];            // Q = V
                P[i * LDSD + lh] = z_[r] * esq;      // P = V·diag(sqrt λ)
            }
        }
        mmb_nt_g(P, Q, sqrtm + c * 1024, tid);       // sqrtm = V diag V^T
        if (half == 1) {
#pragma unroll
            for (int r = 0; r < 32; ++r) P[(r ^ lh) * LDSD + lh] = z_[r] * eisq;
        }
        mmb_nt_g(P, Q, invsqrtm + c * 1024, tid);    // invsqrtm = V diag^-1 V^T
    }
}

// tangent: 4 samples per 256-thread block, per-wave LDS, BARRIER-FREE (wave-synchronous)
__global__ void __launch_bounds__(256) k_tangent(const float* X, const int* labels, const float* sqrtm,
                                                 const float* invsqrtm, float* Tbuf) {
    __shared__ __align__(16) float P[4][MAT], Q[4][MAT];   // 34816 B, per-wave
    int tid = threadIdx.x, wv = tid >> 6, t64 = tid & 63;
    int half = t64 >> 5, lh = tid & 31;
    int b = blockIdx.x * 4 + wv;
    int lb = labels[b];
    float* Pw = P[wv];
    float* Qw = Q[wv];
    g2l<64>(X + b * 1024, Pw, t64);
    g2l<64>(invsqrtm + lb * 1024, Qw, t64);
    mmb_nn(Qw, Pw, Pw, t64);                    // P = S·X      (in-place, wave-private)
    mmb_nn(Pw, Qw, Qw, t64);                    // Q = (S·X)·S = M
    g2l<64>(sqrtm + lb * 1024, Pw, t64);        // P = sqrtm
    float z_[32];
    if (half == 0) {
#pragma unroll
        for (int r = 0; r < 32; ++r) {
            int i = r ^ lh;
            z_[r] = 0.5f * (Qw[i * LDSD + lh] + Qw[lh * LDSD + i]);   // symmetrized M
        }
    } else {
#pragma unroll
        for (int r = 0; r < 32; ++r) z_[r] = Pw[(r ^ lh) * LDSD + lh];  // W0 = sqrtm col (skew)
    }
    rjacobi_split<2>(z_, half, lh);
    float lam = __shfl(z_[0], lh, 64);
    float ev = logf(fmaxf(lam, EV_EPS));
    if (half == 1) {
#pragma unroll
        for (int r = 0; r < 32; ++r) {
            float w = z_[r];
            int i = r ^ lh;
            Qw[i * LDSD + lh] = w;               // Q = W = sqrtm·V
            Pw[i * LDSD + lh] = w * ev;          // P = W·diag(log λ)
        }
    }
    mmb_nt_g(Pw, Qw, Tbuf + b * 1024, t64);      // T = W·diag·W^T
}

// fused: reduce part2 -> meanT (LDS only) -> wave-0 exp-map update -> bary
__global__ void __launch_bounds__(256) k_meanT_update(const float* part2, const int* labels, int B,
                                                      const float* sqrtm, const float* invsqrtm,
                                                      const float* bary0, float* bary) {
    __shared__ __align__(16) float P[MAT], Q[MAT];
    __shared__ int sc[4];
    int c = blockIdx.x, tid = threadIdx.x;
    int cnt = 0;
    for (int b = tid; b < B; b += 256) cnt += (labels[b] == c) ? 1 : 0;
#pragma unroll
    for (int off = 32; off > 0; off >>= 1) cnt += __shfl_down(cnt, off);
    if ((tid & 63) == 0) sc[tid >> 6] = cnt;
    __syncthreads();
    int total = sc[0] + sc[1] + sc[2] + sc[3];
    float acc[4] = {0.f, 0.f, 0.f, 0.f};
    for (int k = 0; k < NPART; ++k) {
#pragma unroll
        for (int e = 0; e < 4; ++e) acc[e] += part2[(k * NC + c) * 1024 + tid + 256 * e];
    }
    float inv = 1.f / (float)total;
#pragma unroll
    for (int e = 0; e < 4; ++e) {
        int idx = tid + 256 * e;
        P[(idx >> 5) * LDSD + (idx & 31)] = acc[e] * inv;   // meanT tile (LDS only)
    }
    __syncthreads();
    if (tid < 64) {
        int half = tid >> 5, lh = tid & 31;
        g2l<64>(invsqrtm + c * 1024, Q, tid);
        mmb_nn(Q, P, P, tid);                    // P = S·meanT
        mmb_nn(P, Q, Q, tid);                    // Q = N
        g2l<64>(sqrtm + c * 1024, P, tid);
        float z_[32];
        if (half == 0) {
#pragma unroll
            for (int r = 0; r < 32; ++r) {
                int i = r ^ lh;
                z_[r] = 0.5f * (Q[i * LDSD + lh] + Q[lh * LDSD + i]);
            }
        } else {
#pragma unroll
            for (int r = 0; r < 32; ++r) z_[r] = P[(r ^ lh) * LDSD + lh];  // W0 = sqrtm col
        }
        rjacobi_split<5>(z_, half, lh);
        float lam = __shfl(z_[0], lh, 64);
        // faithful quirk: clamp eigenvalues to >= 1e-10 BEFORE exp
        float ev = expf(fmaxf(lam, EV_EPS));
        if (half == 1) {
#pragma unroll
            for (int r = 0; r < 32; ++r) {
                float w = z_[r];
                int i = r ^ lh;
                Q[i * LDSD + lh] = w;                // Q = W
                P[i * LDSD + lh] = w * ev;           // P = W·diag(exp λ)
            }
        }
        // newbary tile = P·Q^T per lane; err vs bary0; select; write
        int j2 = (tid & 15) * 2, i0 = (tid >> 4) * 8;
        float2 ac[8];
#pragma unroll
        for (int r = 0; r < 8; ++r) { ac[r].x = 0.f; ac[r].y = 0.f; }
#pragma unroll
        for (int l = 0; l < 32; l += 2) {
            float2 b0 = *(const float2*)&Q[j2 * LDSD + l];
            float2 b1 = *(const float2*)&Q[(j2 + 1) * LDSD + l];
#pragma unroll
            for (int r = 0; r < 8; ++r) {
                float2 a = *(const float2*)&P[(i0 + r) * LDSD + l];
                ac[r].x = fmaf(a.x, b0.x, fmaf(a.y, b0.y, ac[r].x));
                ac[r].y = fmaf(a.x, b1.x, fmaf(a.y, b1.y, ac[r].y));
            }
        }
        float2 bv[8];
        float loc = 0.f;
#pragma unroll
        for (int r = 0; r < 8; ++r) {
            bv[r] = *(const float2*)&bary0[c * 1024 + (i0 + r) * 32 + j2];
            float dx = ac[r].x - bv[r].x, dy = ac[r].y - bv[r].y;
            loc += dx * dx + dy * dy;
        }
#pragma unroll
        for (int off = 32; off > 0; off >>= 1) loc += __shfl_down(loc, off);
        float err2 = __shfl(loc, 0);
        bool keep0 = (err2 < 1e-8f);  // CONV_TOL^2
#pragma unroll
        for (int r = 0; r < 8; ++r) {
            float2 w = keep0 ? bv[r] : ac[r];
            *(float2*)&bary[c * 1024 + (i0 + r) * 32 + j2] = w;
        }
    }
}

// pairdist: fused Cholesky (wave 0, wave-synchronous) + barrier-free per-wave class loop
__global__ void __launch_bounds__(256) k_pairdist(const float* X, const float* bary, float* D) {
    __shared__ __align__(16) float WA[MAT];        // X -> L -> Wt
    __shared__ __align__(16) float BC[4][MAT];     // per-wave class buffer
    int tid = threadIdx.x, wv = tid >> 6, t64 = tid & 63;
    int half = t64 >> 5, lh = tid & 31;
    int b = blockIdx.x;
    g2l<256>(X + b * 1024, WA, tid);
    __syncthreads();                               // WA staged by all 256
    if (tid < 64) {
        // wave-synchronous Cholesky: no barriers (in-order LDS within wave 0)
        if (tid < 32) WA[tid * LDSD + tid] += 1e-3f;   // CHOL_EPS
        for (int k = 0; k < 32; ++k) {
            if (tid == 0) WA[k * LDSD + k] = sqrtf(WA[k * LDSD + k]);
            float invd = fast_rcp(WA[k * LDSD + k]);
            if (tid > k && tid < 32) WA[tid * LDSD + k] *= invd;
            for (int idx = tid; idx < 1024; idx += 64) {
                int i = idx >> 5, j = idx & 31;
                if (i > k && j > k && j <= i) WA[i * LDSD + j] -= WA[i * LDSD + k] * WA[j * LDSD + k];
            }
        }
        // forward substitution: lane j computes column j of W = L^{-1} in registers,
        // then writes row j of Wt = L^{-T} (reads precede writes in wave program order)
        if (tid < 32) {
            const int j = tid;
            float w[32];
#pragma unroll
            for (int i = 0; i < 32; ++i) {
                float acc = (i == j) ? 1.f : 0.f;
#pragma unroll
                for (int k = 0; k < 32; ++k) {
                    if (k < i) acc = fmaf(-WA[i * LDSD + k], w[k], acc);
                }
                float val = acc * fast_rcp(WA[i * LDSD + i]);
                w[i] = (i < j) ? 0.f : val;
            }
#pragma unroll
            for (int i = 0; i < 32; ++i) WA[j * LDSD + i] = w[i];   // Wt row j
        }
    }
    __syncthreads();                               // publish Wt to all waves
    // per-wave, barrier-free: two classes through M = Wt·bary·Wt
    float* Bw = BC[wv];
    float m_[32];
    for (int h = 0; h < 2; ++h) {
        int c = 2 * wv + h;
        g2l<64>(bary + c * 1024, Bw, t64);
        mmb_nn(WA, Bw, Bw, t64);              // Y = Wt·bary  (in-place, wave-private)
        mmb_nn(Bw, WA, Bw, t64);              // M = Y·Wt     (in-place, wave-private)
        if (half == h) {
#pragma unroll
            for (int r = 0; r < 32; ++r) {
                int i = r ^ lh;
                int hi = i > lh ? i : lh, lo = i > lh ? lh : i;  // eigvalsh UPLO='L'
                m_[r] = Bw[hi * LDSD + lo];
            }
        }
    }
    rjacobi_fixed(m_, 2);
    float lg = logf(fmaxf(m_[0], EV_EPS));
    float d2 = lg * lg;
#pragma unroll
    for (int off = 16; off > 0; off >>= 1) d2 += __shfl_xor(d2, off, 32);
    if (lh == 0) D[b * NC + 2 * wv + half] = sqrtf(d2);
}

__global__ void k_loss(const float* out, const int* labels, const float* D, int B, float* res) {
    __shared__ float sI[256], sD[256], sC[256];
    int tid = threadIdx.x;
    float aI = 0.f, aD = 0.f, aC = 0.f;
    for (int b = tid; b < B; b += 256) {
        int lb = labels[b];
        const float* ob = out + b * NC;
        float m = ob[0];
#pragma unroll
        for (int j = 1; j < NC; ++j) m = fmaxf(m, ob[j]);
        float se = 0.f;
#pragma unroll
        for (int j = 0; j < NC; ++j) se += expf(ob[j] - m);
        aC += m + logf(se) - ob[lb];
        const float* db = D + b * NC;
        float s = 0.f;
#pragma unroll
        for (int j = 0; j < NC; ++j) s += db[j];
        aI += db[lb];
        aD += s - db[lb];
    }
    sI[tid] = aI; sD[tid] = aD; sC[tid] = aC;
    __syncthreads();
    for (int off = 128; off > 0; off >>= 1) {
        if (tid < off) { sI[tid] += sI[tid + off]; sD[tid] += sD[tid + off]; sC[tid] += sC[tid + off]; }
        __syncthreads();
    }
    if (tid == 0) {
        float intra = 0.001f * sI[0] / (float)B;
        float disp = sD[0] / (float)(B * (NC - 1));
        float ce = sC[0] / (float)B;
        res[0] = intra - 0.001f * disp + ce;
    }
}

extern "C" void kernel_launch(void* const* d_in, const int* in_sizes, int n_in,
                              void* d_out, int out_size, void* d_ws, size_t ws_size,
                              hipStream_t stream) {
    const float* X = (const float*)d_in[0];
    const float* out = (const float*)d_in[1];
    const int* labels = (const int*)d_in[2];
    int B = in_sizes[2];

    float* ws = (float*)d_ws;
    float* bary0    = ws;                 // 8192
    float* sqrtm    = ws + 8192;          // 8192
    float* invsqrtm = ws + 16384;         // 8192
    float* bary     = ws + 32768;         // 8192
    float* D        = ws + 40960;         // B*8 = 16384
    float* big      = ws + 65536;         // B*1024 floats (partials, then T)
    float* part2    = ws + 65536 + (size_t)B * 1024;  // NPART*NC*1024 floats

    k_accum_part<<<NPART, 256, 0, stream>>>(X, labels, B, big);
    k_bary0_eig<<<NC, 256, 0, stream>>>(big, labels, B, bary0, sqrtm, invsqrtm);
    k_tangent<<<B / 4, 256, 0, stream>>>(X, labels, sqrtm, invsqrtm, big);
    k_accum_part<<<NPART, 256, 0, stream>>>(big, labels, B, part2);
    k_meanT_update<<<NC, 256, 0, stream>>>(part2, labels, B, sqrtm, invsqrtm, bary0, bary);
    k_pairdist<<<B, 256, 0, stream>>>(X, bary, D);
    k_loss<<<1, 256, 0, stream>>>(out, labels, D, B, (float*)d_out);
}

// Round 12
// 2176.116 us; speedup vs baseline: 1.0765x; 1.0765x over previous
//
#include <hip/hip_runtime.h>
#include <math.h>

#define NC 8
#define NDIM 32
#define LDSD 34            // stride 34: rows 8B-aligned (float2); col access 2-way bank alias (free)
#define MAT (NDIM * LDSD)  // 1088 floats per LDS matrix
#define EV_EPS 1e-10f
#define NPART 64

#if __has_builtin(__builtin_amdgcn_rcpf)
__device__ inline float fast_rcp(float x) { return __builtin_amdgcn_rcpf(x); }
#else
__device__ inline float fast_rcp(float x) { return 1.f / x; }
#endif
#if __has_builtin(__builtin_amdgcn_rsqf)
__device__ inline float fast_rsq(float x) { return __builtin_amdgcn_rsqf(x); }
#else
__device__ inline float fast_rsq(float x) { return 1.f / sqrtf(x); }
#endif

// ---------- 32x32 LDS helpers ----------
template <int NT>
__device__ inline void g2l(const float* g, float* l, int t) {
    for (int idx2 = t; idx2 < 512; idx2 += NT) {
        int i = idx2 >> 4, jp = idx2 & 15;
        *(float2*)&l[i * LDSD + 2 * jp] = *(const float2*)&g[i * 32 + 2 * jp];
    }
}

// ---------- register-tiled LDS matmuls (one wave; 8-row x 2-col tile/lane; t = 0..63) ----------
// C = A * B.  Wave-private safe for ANY aliasing (C==A or C==B): all read
// instructions precede all stores in the wave's in-order instruction stream.
__device__ inline void mmb_nn(const float* A, const float* B, float* C, int t) {
    int j2 = (t & 15) * 2;
    int i0 = (t >> 4) * 8;
    float2 ac[8];
#pragma unroll
    for (int r = 0; r < 8; ++r) { ac[r].x = 0.f; ac[r].y = 0.f; }
#pragma unroll
    for (int k = 0; k < 32; k += 2) {
        float2 b0 = *(const float2*)&B[k * LDSD + j2];
        float2 b1 = *(const float2*)&B[(k + 1) * LDSD + j2];
#pragma unroll
        for (int r = 0; r < 8; ++r) {
            float2 a = *(const float2*)&A[(i0 + r) * LDSD + k];
            ac[r].x = fmaf(a.x, b0.x, fmaf(a.y, b1.x, ac[r].x));
            ac[r].y = fmaf(a.x, b0.y, fmaf(a.y, b1.y, ac[r].y));
        }
    }
#pragma unroll
    for (int r = 0; r < 8; ++r) *(float2*)&C[(i0 + r) * LDSD + j2] = ac[r];
}
// gC(global, stride 32) = A * B^T
__device__ inline void mmb_nt_g(const float* A, const float* B, float* gC, int t) {
    int j2 = (t & 15) * 2;
    int i0 = (t >> 4) * 8;
    float2 ac[8];
#pragma unroll
    for (int r = 0; r < 8; ++r) { ac[r].x = 0.f; ac[r].y = 0.f; }
#pragma unroll
    for (int l = 0; l < 32; l += 2) {
        float2 b0 = *(const float2*)&B[j2 * LDSD + l];
        float2 b1 = *(const float2*)&B[(j2 + 1) * LDSD + l];
#pragma unroll
        for (int r = 0; r < 8; ++r) {
            float2 a = *(const float2*)&A[(i0 + r) * LDSD + l];
            ac[r].x = fmaf(a.x, b0.x, fmaf(a.y, b0.y, ac[r].x));
            ac[r].y = fmaf(a.x, b1.x, fmaf(a.y, b1.y, ac[r].y));
        }
    }
#pragma unroll
    for (int r = 0; r < 8; ++r) *(float2*)&gC[(i0 + r) * 32 + j2] = ac[r];
}

// ---------- register-resident XOR-ordered Jacobi, eigenvalues only, fixed sweeps ----------
// Lane lh holds column lh skewed: m_[r] = M[r^lh][lh]; diag = m_[0].
__device__ inline void rjacobi_fixed(float* m_, int nsweep) {
    for (int sweep = 0; sweep < nsweep; ++sweep) {
#pragma unroll
        for (int mm = 1; mm < 32; ++mm) {
            float app = m_[0];
            float aqq = __shfl_xor(app, mm, 32);
            float apq = m_[mm];
            float apqc = __builtin_copysignf(fmaxf(fabsf(apq), 1e-36f), apq);
            float tau = (aqq - app) * 0.5f * fast_rcp(apqc);
            float den = fabsf(tau) + sqrtf(fmaf(tau, tau, 1.f));
            float t = __builtin_copysignf(fast_rcp(den), tau);
            t = (fabsf(apq) > 1e-36f) ? t : 0.f;
            float cc = fast_rsq(fmaf(t, t, 1.f));
            float ss = t * cc;
#pragma unroll
            for (int r = 0; r < 32; ++r) {
                if (r < (r ^ mm)) {
                    const int r2 = r ^ mm;
                    float ti = __shfl_xor(t, r, 32);
                    float ci = fast_rsq(fmaf(ti, ti, 1.f));
                    float si = ti * ci;
                    float x = m_[r], y = m_[r2];
                    m_[r]  = ci * x - si * y;
                    m_[r2] = ci * y + si * x;
                }
            }
            float o[32];
#pragma unroll
            for (int u = 0; u < 32; ++u) o[u] = __shfl_xor(m_[u ^ mm], mm, 32);
#pragma unroll
            for (int u = 0; u < 32; ++u) m_[u] = fmaf(cc, m_[u], -ss * o[u]);
        }
    }
}

// ---------- split-role register Jacobi: half 0 solves M, half 1 accumulates W·V ----------
template <int NSWEEP>
__device__ inline void rjacobi_split(float* z_, int half, int lh) {
    for (int sweep = 0; sweep < NSWEEP; ++sweep) {
#pragma unroll
        for (int mm = 1; mm < 32; ++mm) {
            float app = z_[0];
            float aqq = __shfl_xor(app, mm, 32);
            float apq = z_[mm];
            float apqc = __builtin_copysignf(fmaxf(fabsf(apq), 1e-36f), apq);
            float tau = (aqq - app) * 0.5f * fast_rcp(apqc);
            float den = fabsf(tau) + sqrtf(fmaf(tau, tau, 1.f));
            float t = __builtin_copysignf(fast_rcp(den), tau);
            t = (fabsf(apq) > 1e-36f) ? t : 0.f;
            t = __shfl(t, lh, 64);               // half 1 inherits half 0's t (wave-local)
            float cc = fast_rsq(fmaf(t, t, 1.f));
            float ss = t * cc;
            if (half == 0) {                     // row rotations on M only (t-refetch)
#pragma unroll
                for (int r = 0; r < 32; ++r) {
                    if (r < (r ^ mm)) {
                        const int r2 = r ^ mm;
                        float ti = __shfl_xor(t, r, 32);
                        float ci = fast_rsq(fmaf(ti, ti, 1.f));
                        float si = ti * ci;
                        float x = z_[r], y = z_[r2];
                        z_[r]  = ci * x - si * y;
                        z_[r2] = ci * y + si * x;
                    }
                }
            }
            float o[32];
#pragma unroll
            for (int u = 0; u < 32; ++u) o[u] = __shfl_xor(z_[u ^ mm], mm, 32);
#pragma unroll
            for (int u = 0; u < 32; ++u) z_[u] = fmaf(cc, z_[u], -ss * o[u]);
        }
    }
}

// ---------- kernels ----------
__global__ void __launch_bounds__(256) k_accum_part(const float* src, const int* labels, int B, float* part) {
    int blk = blockIdx.x, tid = threadIdx.x;
    int chunk = (B + NPART - 1) / NPART;
    int b0 = blk * chunk, b1 = b0 + chunk < B ? b0 + chunk : B;
    float acc[NC][4];
#pragma unroll
    for (int c = 0; c < NC; ++c)
#pragma unroll
        for (int e = 0; e < 4; ++e) acc[c][e] = 0.f;
    for (int b = b0; b < b1; ++b) {
        int lb = labels[b];
        float x[4];
#pragma unroll
        for (int e = 0; e < 4; ++e) x[e] = src[b * 1024 + tid + 256 * e];
#pragma unroll
        for (int c = 0; c < NC; ++c) {
            if (lb == c) {
#pragma unroll
                for (int e = 0; e < 4; ++e) acc[c][e] += x[e];
            }
        }
    }
#pragma unroll
    for (int c = 0; c < NC; ++c)
#pragma unroll
        for (int e = 0; e < 4; ++e) part[(blk * NC + c) * 1024 + tid + 256 * e] = acc[c][e];
}

// fused: reduce partials -> bary0 (global + LDS tile) -> wave-0 eigen -> sqrtm/invsqrtm
__global__ void __launch_bounds__(256) k_bary0_eig(const float* part, const int* labels, int B,
                                                   float* bary0, float* sqrtm, float* invsqrtm) {
    __shared__ __align__(16) float P[MAT], Q[MAT];
    __shared__ int sc[4];
    int c = blockIdx.x, tid = threadIdx.x;
    int cnt = 0;
    for (int b = tid; b < B; b += 256) cnt += (labels[b] == c) ? 1 : 0;
#pragma unroll
    for (int off = 32; off > 0; off >>= 1) cnt += __shfl_down(cnt, off);
    if ((tid & 63) == 0) sc[tid >> 6] = cnt;
    __syncthreads();
    int total = sc[0] + sc[1] + sc[2] + sc[3];
    float acc[4] = {0.f, 0.f, 0.f, 0.f};
    for (int k = 0; k < NPART; ++k) {
#pragma unroll
        for (int e = 0; e < 4; ++e) acc[e] += part[(k * NC + c) * 1024 + tid + 256 * e];
    }
    float inv = 1.f / (float)total;
#pragma unroll
    for (int e = 0; e < 4; ++e) {
        int idx = tid + 256 * e;
        float v = acc[e] * inv;
        P[(idx >> 5) * LDSD + (idx & 31)] = v;
        bary0[c * 1024 + idx] = v;
    }
    __syncthreads();
    if (tid < 64) {
        int half = tid >> 5, lh = tid & 31;
        float z_[32];
        if (half == 0) {
#pragma unroll
            for (int r = 0; r < 32; ++r) {
                int i = r ^ lh;
                z_[r] = 0.5f * (P[i * LDSD + lh] + P[lh * LDSD + i]);
            }
        } else {
#pragma unroll
            for (int r = 0; r < 32; ++r) z_[r] = (r == 0) ? 1.f : 0.f;   // V0 = I col
        }
        rjacobi_split<5>(z_, half, lh);
        float lam = __shfl(z_[0], lh, 64);
        float esq = sqrtf(fmaxf(lam, 0.f));
        float eisq = fast_rsq(fmaxf(lam, 1e-30f));
        if (half == 1) {
#pragma unroll
            for (int r = 0; r < 32; ++r) {
                int i = r ^ lh;
                Q[i * LDSD + lh] = z_[r];            // Q = V
                P[i * LDSD + lh] = z_[r] * esq;      // P = V·diag(sqrt λ)
            }
        }
        mmb_nt_g(P, Q, sqrtm + c * 1024, tid);       // sqrtm = V diag V^T
        if (half == 1) {
#pragma unroll
            for (int r = 0; r < 32; ++r) P[(r ^ lh) * LDSD + lh] = z_[r] * eisq;
        }
        mmb_nt_g(P, Q, invsqrtm + c * 1024, tid);    // invsqrtm = V diag^-1 V^T
    }
}

// tangent: 4 samples per 256-thread block (per-wave P,Q); split-role wave; 2 sweeps (round-10 form)
__global__ void __launch_bounds__(256) k_tangent(const float* X, const int* labels, const float* sqrtm,
                                                 const float* invsqrtm, float* Tbuf) {
    __shared__ __align__(16) float P[4][MAT], Q[4][MAT];   // 34816 B, per-wave
    int tid = threadIdx.x, wv = tid >> 6, t64 = tid & 63;
    int half = t64 >> 5, lh = tid & 31;
    int b = blockIdx.x * 4 + wv;
    int lb = labels[b];
    float* Pw = P[wv];
    float* Qw = Q[wv];
    g2l<64>(X + b * 1024, Pw, t64);
    g2l<64>(invsqrtm + lb * 1024, Qw, t64);
    __syncthreads();
    mmb_nn(Qw, Pw, Pw, t64); __syncthreads();   // P = S·X
    mmb_nn(Pw, Qw, Qw, t64); __syncthreads();   // Q = (S·X)·S = M
    g2l<64>(sqrtm + lb * 1024, Pw, t64);        // P = sqrtm
    __syncthreads();
    float z_[32];
    if (half == 0) {
#pragma unroll
        for (int r = 0; r < 32; ++r) {
            int i = r ^ lh;
            z_[r] = 0.5f * (Qw[i * LDSD + lh] + Qw[lh * LDSD + i]);   // symmetrized M
        }
    } else {
#pragma unroll
        for (int r = 0; r < 32; ++r) z_[r] = Pw[(r ^ lh) * LDSD + lh];  // W0 = sqrtm col (skew)
    }
    rjacobi_split<2>(z_, half, lh);
    float lam = __shfl(z_[0], lh, 64);          // wave-local broadcast of half-0 eigenvalue
    float ev = logf(fmaxf(lam, EV_EPS));
    __syncthreads();                             // extraction reads of P,Q done
    if (half == 1) {
#pragma unroll
        for (int r = 0; r < 32; ++r) {
            float w = z_[r];
            int i = r ^ lh;
            Qw[i * LDSD + lh] = w;               // Q = W = sqrtm·V
            Pw[i * LDSD + lh] = w * ev;          // P = W·diag(log λ)
        }
    }
    __syncthreads();
    mmb_nt_g(Pw, Qw, Tbuf + b * 1024, t64);      // T = W·diag·W^T
}

// fused: reduce part2 -> meanT (LDS only) -> wave-0 exp-map update -> bary
__global__ void __launch_bounds__(256) k_meanT_update(const float* part2, const int* labels, int B,
                                                      const float* sqrtm, const float* invsqrtm,
                                                      const float* bary0, float* bary) {
    __shared__ __align__(16) float P[MAT], Q[MAT];
    __shared__ int sc[4];
    int c = blockIdx.x, tid = threadIdx.x;
    int cnt = 0;
    for (int b = tid; b < B; b += 256) cnt += (labels[b] == c) ? 1 : 0;
#pragma unroll
    for (int off = 32; off > 0; off >>= 1) cnt += __shfl_down(cnt, off);
    if ((tid & 63) == 0) sc[tid >> 6] = cnt;
    __syncthreads();
    int total = sc[0] + sc[1] + sc[2] + sc[3];
    float acc[4] = {0.f, 0.f, 0.f, 0.f};
    for (int k = 0; k < NPART; ++k) {
#pragma unroll
        for (int e = 0; e < 4; ++e) acc[e] += part2[(k * NC + c) * 1024 + tid + 256 * e];
    }
    float inv = 1.f / (float)total;
#pragma unroll
    for (int e = 0; e < 4; ++e) {
        int idx = tid + 256 * e;
        P[(idx >> 5) * LDSD + (idx & 31)] = acc[e] * inv;   // meanT tile (LDS only)
    }
    __syncthreads();
    if (tid < 64) {
        int half = tid >> 5, lh = tid & 31;
        g2l<64>(invsqrtm + c * 1024, Q, tid);
        mmb_nn(Q, P, P, tid);                    // P = S·meanT
        mmb_nn(P, Q, Q, tid);                    // Q = N
        g2l<64>(sqrtm + c * 1024, P, tid);
        float z_[32];
        if (half == 0) {
#pragma unroll
            for (int r = 0; r < 32; ++r) {
                int i = r ^ lh;
                z_[r] = 0.5f * (Q[i * LDSD + lh] + Q[lh * LDSD + i]);
            }
        } else {
#pragma unroll
            for (int r = 0; r < 32; ++r) z_[r] = P[(r ^ lh) * LDSD + lh];  // W0 = sqrtm col
        }
        rjacobi_split<5>(z_, half, lh);
        float lam = __shfl(z_[0], lh, 64);
        // faithful quirk: clamp eigenvalues to >= 1e-10 BEFORE exp
        float ev = expf(fmaxf(lam, EV_EPS));
        if (half == 1) {
#pragma unroll
            for (int r = 0; r < 32; ++r) {
                float w = z_[r];
                int i = r ^ lh;
                Q[i * LDSD + lh] = w;                // Q = W
                P[i * LDSD + lh] = w * ev;           // P = W·diag(exp λ)
            }
        }
        // newbary tile = P·Q^T per lane; err vs bary0; select; write
        int j2 = (tid & 15) * 2, i0 = (tid >> 4) * 8;
        float2 ac[8];
#pragma unroll
        for (int r = 0; r < 8; ++r) { ac[r].x = 0.f; ac[r].y = 0.f; }
#pragma unroll
        for (int l = 0; l < 32; l += 2) {
            float2 b0 = *(const float2*)&Q[j2 * LDSD + l];
            float2 b1 = *(const float2*)&Q[(j2 + 1) * LDSD + l];
#pragma unroll
            for (int r = 0; r < 8; ++r) {
                float2 a = *(const float2*)&P[(i0 + r) * LDSD + l];
                ac[r].x = fmaf(a.x, b0.x, fmaf(a.y, b0.y, ac[r].x));
                ac[r].y = fmaf(a.x, b1.x, fmaf(a.y, b1.y, ac[r].y));
            }
        }
        float2 bv[8];
        float loc = 0.f;
#pragma unroll
        for (int r = 0; r < 8; ++r) {
            bv[r] = *(const float2*)&bary0[c * 1024 + (i0 + r) * 32 + j2];
            float dx = ac[r].x - bv[r].x, dy = ac[r].y - bv[r].y;
            loc += dx * dx + dy * dy;
        }
#pragma unroll
        for (int off = 32; off > 0; off >>= 1) loc += __shfl_down(loc, off);
        float err2 = __shfl(loc, 0);
        bool keep0 = (err2 < 1e-8f);  // CONV_TOL^2
#pragma unroll
        for (int r = 0; r < 8; ++r) {
            float2 w = keep0 ? bv[r] : ac[r];
            *(float2*)&bary[c * 1024 + (i0 + r) * 32 + j2] = w;
        }
    }
}

// pairdist: round-10 barriered Cholesky (256 threads) + BARRIER-FREE per-wave class loop
__global__ void __launch_bounds__(256) k_pairdist(const float* X, const float* bary, float* D) {
    __shared__ __align__(16) float WA[MAT];        // X -> L -> Wt
    __shared__ __align__(16) float BC[4][MAT];     // per-wave class buffer
    int tid = threadIdx.x, wv = tid >> 6, t64 = tid & 63;
    int half = t64 >> 5, lh = tid & 31;
    int b = blockIdx.x;
    g2l<256>(X + b * 1024, WA, tid);
    __syncthreads();
    if (tid < 32) WA[tid * LDSD + tid] += 1e-3f;   // CHOL_EPS
    __syncthreads();
    // right-looking Cholesky (lower triangle), 256 threads on trailing updates (round-10 form)
    for (int k = 0; k < 32; ++k) {
        if (tid == 0) WA[k * LDSD + k] = sqrtf(WA[k * LDSD + k]);
        __syncthreads();
        float invd = fast_rcp(WA[k * LDSD + k]);
        if (tid > k && tid < 32) WA[tid * LDSD + k] *= invd;
        __syncthreads();
        for (int idx = tid; idx < 1024; idx += 256) {
            int i = idx >> 5, j = idx & 31;
            if (i > k && j > k && j <= i) WA[i * LDSD + j] -= WA[i * LDSD + k] * WA[j * LDSD + k];
        }
        __syncthreads();
    }
    // forward substitution: lane j computes column j of W = L^{-1} in registers,
    // then writes row j of Wt = L^{-T} (reads precede writes in wave program order)
    if (tid < 32) {
        const int j = tid;
        float w[32];
#pragma unroll
        for (int i = 0; i < 32; ++i) {
            float acc = (i == j) ? 1.f : 0.f;
#pragma unroll
            for (int k = 0; k < 32; ++k) {
                if (k < i) acc = fmaf(-WA[i * LDSD + k], w[k], acc);
            }
            float val = acc * fast_rcp(WA[i * LDSD + i]);
            w[i] = (i < j) ? 0.f : val;
        }
#pragma unroll
        for (int i = 0; i < 32; ++i) WA[j * LDSD + i] = w[i];   // Wt row j
    }
    __syncthreads();                               // publish Wt to all waves
    // per-wave class loop: NO block barriers (Bw wave-private, WA read-only).
    // #pragma unroll 1 keeps the two iterations separate (prevents register blow-up).
    float* Bw = BC[wv];
    float m_[32];
#pragma unroll 1
    for (int h = 0; h < 2; ++h) {
        int c = 2 * wv + h;
        g2l<64>(bary + c * 1024, Bw, t64);
        mmb_nn(WA, Bw, Bw, t64);              // Y = Wt·bary  (in-place, wave-private)
        mmb_nn(Bw, WA, Bw, t64);              // M = Y·Wt     (in-place, wave-private)
        if (half == h) {
#pragma unroll
            for (int r = 0; r < 32; ++r) {
                int i = r ^ lh;
                int hi = i > lh ? i : lh, lo = i > lh ? lh : i;  // eigvalsh UPLO='L'
                m_[r] = Bw[hi * LDSD + lo];
            }
        }
    }
    rjacobi_fixed(m_, 2);
    float lg = logf(fmaxf(m_[0], EV_EPS));
    float d2 = lg * lg;
#pragma unroll
    for (int off = 16; off > 0; off >>= 1) d2 += __shfl_xor(d2, off, 32);
    if (lh == 0) D[b * NC + 2 * wv + half] = sqrtf(d2);
}

__global__ void k_loss(const float* out, const int* labels, const float* D, int B, float* res) {
    __shared__ float sI[256], sD[256], sC[256];
    int tid = threadIdx.x;
    float aI = 0.f, aD = 0.f, aC = 0.f;
    for (int b = tid; b < B; b += 256) {
        int lb = labels[b];
        const float* ob = out + b * NC;
        float m = ob[0];
#pragma unroll
        for (int j = 1; j < NC; ++j) m = fmaxf(m, ob[j]);
        float se = 0.f;
#pragma unroll
        for (int j = 0; j < NC; ++j) se += expf(ob[j] - m);
        aC += m + logf(se) - ob[lb];
        const float* db = D + b * NC;
        float s = 0.f;
#pragma unroll
        for (int j = 0; j < NC; ++j) s += db[j];
        aI += db[lb];
        aD += s - db[lb];
    }
    sI[tid] = aI; sD[tid] = aD; sC[tid] = aC;
    __syncthreads();
    for (int off = 128; off > 0; off >>= 1) {
        if (tid < off) { sI[tid] += sI[tid + off]; sD[tid] += sD[tid + off]; sC[tid] += sC[tid + off]; }
        __syncthreads();
    }
    if (tid == 0) {
        float intra = 0.001f * sI[0] / (float)B;
        float disp = sD[0] / (float)(B * (NC - 1));
        float ce = sC[0] / (float)B;
        res[0] = intra - 0.001f * disp + ce;
    }
}

extern "C" void kernel_launch(void* const* d_in, const int* in_sizes, int n_in,
                              void* d_out, int out_size, void* d_ws, size_t ws_size,
                              hipStream_t stream) {
    const float* X = (const float*)d_in[0];
    const float* out = (const float*)d_in[1];
    const int* labels = (const int*)d_in[2];
    int B = in_sizes[2];

    float* ws = (float*)d_ws;
    float* bary0    = ws;                 // 8192
    float* sqrtm    = ws + 8192;          // 8192
    float* invsqrtm = ws + 16384;         // 8192
    float* bary     = ws + 32768;         // 8192
    float* D        = ws + 40960;         // B*8 = 16384
    float* big      = ws + 65536;         // B*1024 floats (partials, then T)
    float* part2    = ws + 65536 + (size_t)B * 1024;  // NPART*NC*1024 floats

    k_accum_part<<<NPART, 256, 0, stream>>>(X, labels, B, big);
    k_bary0_eig<<<NC, 256, 0, stream>>>(big, labels, B, bary0, sqrtm, invsqrtm);
    k_tangent<<<B / 4, 256, 0, stream>>>(X, labels, sqrtm, invsqrtm, big);
    k_accum_part<<<NPART, 256, 0, stream>>>(big, labels, B, part2);
    k_meanT_update<<<NC, 256, 0, stream>>>(part2, labels, B, sqrtm, invsqrtm, bary0, bary);
    k_pairdist<<<B, 256, 0, stream>>>(X, bary, D);
    k_loss<<<1, 256, 0, stream>>>(out, labels, D, B, (float*)d_out);
}

// Round 13
// 1174.618 us; speedup vs baseline: 1.9943x; 1.8526x over previous
//
#include <hip/hip_runtime.h>
#include <math.h>

#define NC 8
#define NDIM 32
#define LDSD 34            // stride 34: rows 8B-aligned (float2); col access 2-way bank alias (free)
#define MAT (NDIM * LDSD)  // 1088 floats per LDS matrix
#define EV_EPS 1e-10f
#define NPART 64

#if __has_builtin(__builtin_amdgcn_rcpf)
__device__ inline float fast_rcp(float x) { return __builtin_amdgcn_rcpf(x); }
#else
__device__ inline float fast_rcp(float x) { return 1.f / x; }
#endif
#if __has_builtin(__builtin_amdgcn_rsqf)
__device__ inline float fast_rsq(float x) { return __builtin_amdgcn_rsqf(x); }
#else
__device__ inline float fast_rsq(float x) { return 1.f / sqrtf(x); }
#endif

#define SCHED_FENCE() __builtin_amdgcn_sched_barrier(0)

// ---------- 32x32 LDS helpers ----------
template <int NT>
__device__ inline void g2l(const float* g, float* l, int t) {
    for (int idx2 = t; idx2 < 512; idx2 += NT) {
        int i = idx2 >> 4, jp = idx2 & 15;
        *(float2*)&l[i * LDSD + 2 * jp] = *(const float2*)&g[i * 32 + 2 * jp];
    }
}

// ---------- register-tiled LDS matmuls (one wave; 8-row x 2-col tile/lane; t = 0..63) ----------
// C = A * B.  Wave-private safe for ANY aliasing (C==A or C==B): all read
// instructions precede all stores in the wave's in-order instruction stream.
__device__ inline void mmb_nn(const float* A, const float* B, float* C, int t) {
    int j2 = (t & 15) * 2;
    int i0 = (t >> 4) * 8;
    float2 ac[8];
#pragma unroll
    for (int r = 0; r < 8; ++r) { ac[r].x = 0.f; ac[r].y = 0.f; }
#pragma unroll
    for (int k = 0; k < 32; k += 2) {
        float2 b0 = *(const float2*)&B[k * LDSD + j2];
        float2 b1 = *(const float2*)&B[(k + 1) * LDSD + j2];
#pragma unroll
        for (int r = 0; r < 8; ++r) {
            float2 a = *(const float2*)&A[(i0 + r) * LDSD + k];
            ac[r].x = fmaf(a.x, b0.x, fmaf(a.y, b1.x, ac[r].x));
            ac[r].y = fmaf(a.x, b0.y, fmaf(a.y, b1.y, ac[r].y));
        }
    }
#pragma unroll
    for (int r = 0; r < 8; ++r) *(float2*)&C[(i0 + r) * LDSD + j2] = ac[r];
}
// gC(global, stride 32) = A * B^T
__device__ inline void mmb_nt_g(const float* A, const float* B, float* gC, int t) {
    int j2 = (t & 15) * 2;
    int i0 = (t >> 4) * 8;
    float2 ac[8];
#pragma unroll
    for (int r = 0; r < 8; ++r) { ac[r].x = 0.f; ac[r].y = 0.f; }
#pragma unroll
    for (int l = 0; l < 32; l += 2) {
        float2 b0 = *(const float2*)&B[j2 * LDSD + l];
        float2 b1 = *(const float2*)&B[(j2 + 1) * LDSD + l];
#pragma unroll
        for (int r = 0; r < 8; ++r) {
            float2 a = *(const float2*)&A[(i0 + r) * LDSD + l];
            ac[r].x = fmaf(a.x, b0.x, fmaf(a.y, b0.y, ac[r].x));
            ac[r].y = fmaf(a.x, b1.x, fmaf(a.y, b1.y, ac[r].y));
        }
    }
#pragma unroll
    for (int r = 0; r < 8; ++r) *(float2*)&gC[(i0 + r) * 32 + j2] = ac[r];
}

// ---------- register-resident XOR-ordered Jacobi, eigenvalues only, fixed sweeps ----------
// Lane lh holds column lh skewed: m_[r] = M[r^lh][lh]; diag = m_[0].
__device__ inline void rjacobi_fixed(float* m_, int nsweep) {
    for (int sweep = 0; sweep < nsweep; ++sweep) {
#pragma unroll
        for (int mm = 1; mm < 32; ++mm) {
            float app = m_[0];
            float aqq = __shfl_xor(app, mm, 32);
            float apq = m_[mm];
            float apqc = __builtin_copysignf(fmaxf(fabsf(apq), 1e-36f), apq);
            float tau = (aqq - app) * 0.5f * fast_rcp(apqc);
            float den = fabsf(tau) + sqrtf(fmaf(tau, tau, 1.f));
            float t = __builtin_copysignf(fast_rcp(den), tau);
            t = (fabsf(apq) > 1e-36f) ? t : 0.f;
            float cc = fast_rsq(fmaf(t, t, 1.f));
            float ss = t * cc;
#pragma unroll
            for (int r = 0; r < 32; ++r) {
                if (r < (r ^ mm)) {
                    const int r2 = r ^ mm;
                    float ti = __shfl_xor(t, r, 32);
                    float ci = fast_rsq(fmaf(ti, ti, 1.f));
                    float si = ti * ci;
                    float x = m_[r], y = m_[r2];
                    m_[r]  = ci * x - si * y;
                    m_[r2] = ci * y + si * x;
                }
            }
            float o[32];
#pragma unroll
            for (int u = 0; u < 32; ++u) o[u] = __shfl_xor(m_[u ^ mm], mm, 32);
#pragma unroll
            for (int u = 0; u < 32; ++u) m_[u] = fmaf(cc, m_[u], -ss * o[u]);
        }
    }
}

// ---------- split-role register Jacobi: half 0 solves M, half 1 accumulates W·V ----------
template <int NSWEEP>
__device__ inline void rjacobi_split(float* z_, int half, int lh) {
    for (int sweep = 0; sweep < NSWEEP; ++sweep) {
#pragma unroll
        for (int mm = 1; mm < 32; ++mm) {
            float app = z_[0];
            float aqq = __shfl_xor(app, mm, 32);
            float apq = z_[mm];
            float apqc = __builtin_copysignf(fmaxf(fabsf(apq), 1e-36f), apq);
            float tau = (aqq - app) * 0.5f * fast_rcp(apqc);
            float den = fabsf(tau) + sqrtf(fmaf(tau, tau, 1.f));
            float t = __builtin_copysignf(fast_rcp(den), tau);
            t = (fabsf(apq) > 1e-36f) ? t : 0.f;
            t = __shfl(t, lh, 64);               // half 1 inherits half 0's t (wave-local)
            float cc = fast_rsq(fmaf(t, t, 1.f));
            float ss = t * cc;
            if (half == 0) {                     // row rotations on M only (t-refetch)
#pragma unroll
                for (int r = 0; r < 32; ++r) {
                    if (r < (r ^ mm)) {
                        const int r2 = r ^ mm;
                        float ti = __shfl_xor(t, r, 32);
                        float ci = fast_rsq(fmaf(ti, ti, 1.f));
                        float si = ti * ci;
                        float x = z_[r], y = z_[r2];
                        z_[r]  = ci * x - si * y;
                        z_[r2] = ci * y + si * x;
                    }
                }
            }
            float o[32];
#pragma unroll
            for (int u = 0; u < 32; ++u) o[u] = __shfl_xor(z_[u ^ mm], mm, 32);
#pragma unroll
            for (int u = 0; u < 32; ++u) z_[u] = fmaf(cc, z_[u], -ss * o[u]);
        }
    }
}

// ---------- kernels ----------
__global__ void __launch_bounds__(256) k_accum_part(const float* src, const int* labels, int B, float* part) {
    int blk = blockIdx.x, tid = threadIdx.x;
    int chunk = (B + NPART - 1) / NPART;
    int b0 = blk * chunk, b1 = b0 + chunk < B ? b0 + chunk : B;
    float acc[NC][4];
#pragma unroll
    for (int c = 0; c < NC; ++c)
#pragma unroll
        for (int e = 0; e < 4; ++e) acc[c][e] = 0.f;
    for (int b = b0; b < b1; ++b) {
        int lb = labels[b];
        float x[4];
#pragma unroll
        for (int e = 0; e < 4; ++e) x[e] = src[b * 1024 + tid + 256 * e];
#pragma unroll
        for (int c = 0; c < NC; ++c) {
            if (lb == c) {
#pragma unroll
                for (int e = 0; e < 4; ++e) acc[c][e] += x[e];
            }
        }
    }
#pragma unroll
    for (int c = 0; c < NC; ++c)
#pragma unroll
        for (int e = 0; e < 4; ++e) part[(blk * NC + c) * 1024 + tid + 256 * e] = acc[c][e];
}

// fused: reduce partials -> bary0 (global + LDS tile) -> wave-0 eigen -> sqrtm/invsqrtm
__global__ void __launch_bounds__(256) k_bary0_eig(const float* part, const int* labels, int B,
                                                   float* bary0, float* sqrtm, float* invsqrtm) {
    __shared__ __align__(16) float P[MAT], Q[MAT];
    __shared__ int sc[4];
    int c = blockIdx.x, tid = threadIdx.x;
    int cnt = 0;
    for (int b = tid; b < B; b += 256) cnt += (labels[b] == c) ? 1 : 0;
#pragma unroll
    for (int off = 32; off > 0; off >>= 1) cnt += __shfl_down(cnt, off);
    if ((tid & 63) == 0) sc[tid >> 6] = cnt;
    __syncthreads();
    int total = sc[0] + sc[1] + sc[2] + sc[3];
    float acc[4] = {0.f, 0.f, 0.f, 0.f};
    for (int k = 0; k < NPART; ++k) {
#pragma unroll
        for (int e = 0; e < 4; ++e) acc[e] += part[(k * NC + c) * 1024 + tid + 256 * e];
    }
    float inv = 1.f / (float)total;
#pragma unroll
    for (int e = 0; e < 4; ++e) {
        int idx = tid + 256 * e;
        float v = acc[e] * inv;
        P[(idx >> 5) * LDSD + (idx & 31)] = v;
        bary0[c * 1024 + idx] = v;
    }
    __syncthreads();
    if (tid < 64) {
        int half = tid >> 5, lh = tid & 31;
        float z_[32];
        if (half == 0) {
#pragma unroll
            for (int r = 0; r < 32; ++r) {
                int i = r ^ lh;
                z_[r] = 0.5f * (P[i * LDSD + lh] + P[lh * LDSD + i]);
            }
        } else {
#pragma unroll
            for (int r = 0; r < 32; ++r) z_[r] = (r == 0) ? 1.f : 0.f;   // V0 = I col
        }
        rjacobi_split<5>(z_, half, lh);
        float lam = __shfl(z_[0], lh, 64);
        float esq = sqrtf(fmaxf(lam, 0.f));
        float eisq = fast_rsq(fmaxf(lam, 1e-30f));
        if (half == 1) {
#pragma unroll
            for (int r = 0; r < 32; ++r) {
                int i = r ^ lh;
                Q[i * LDSD + lh] = z_[r];            // Q = V
                P[i * LDSD + lh] = z_[r] * esq;      // P = V·diag(sqrt λ)
            }
        }
        mmb_nt_g(P, Q, sqrtm + c * 1024, tid);       // sqrtm = V diag V^T
        if (half == 1) {
#pragma unroll
            for (int r = 0; r < 32; ++r) P[(r ^ lh) * LDSD + lh] = z_[r] * eisq;
        }
        mmb_nt_g(P, Q, invsqrtm + c * 1024, tid);    // invsqrtm = V diag^-1 V^T
    }
}

// tangent: 4 samples per 256-thread block (per-wave P,Q); split-role wave; 2 sweeps (round-10 form)
__global__ void __launch_bounds__(256) k_tangent(const float* X, const int* labels, const float* sqrtm,
                                                 const float* invsqrtm, float* Tbuf) {
    __shared__ __align__(16) float P[4][MAT], Q[4][MAT];   // 34816 B, per-wave
    int tid = threadIdx.x, wv = tid >> 6, t64 = tid & 63;
    int half = t64 >> 5, lh = tid & 31;
    int b = blockIdx.x * 4 + wv;
    int lb = labels[b];
    float* Pw = P[wv];
    float* Qw = Q[wv];
    g2l<64>(X + b * 1024, Pw, t64);
    g2l<64>(invsqrtm + lb * 1024, Qw, t64);
    __syncthreads();
    mmb_nn(Qw, Pw, Pw, t64); __syncthreads();   // P = S·X
    mmb_nn(Pw, Qw, Qw, t64); __syncthreads();   // Q = (S·X)·S = M
    g2l<64>(sqrtm + lb * 1024, Pw, t64);        // P = sqrtm
    __syncthreads();
    float z_[32];
    if (half == 0) {
#pragma unroll
        for (int r = 0; r < 32; ++r) {
            int i = r ^ lh;
            z_[r] = 0.5f * (Qw[i * LDSD + lh] + Qw[lh * LDSD + i]);   // symmetrized M
        }
    } else {
#pragma unroll
        for (int r = 0; r < 32; ++r) z_[r] = Pw[(r ^ lh) * LDSD + lh];  // W0 = sqrtm col (skew)
    }
    rjacobi_split<2>(z_, half, lh);
    float lam = __shfl(z_[0], lh, 64);          // wave-local broadcast of half-0 eigenvalue
    float ev = logf(fmaxf(lam, EV_EPS));
    __syncthreads();                             // extraction reads of P,Q done
    if (half == 1) {
#pragma unroll
        for (int r = 0; r < 32; ++r) {
            float w = z_[r];
            int i = r ^ lh;
            Qw[i * LDSD + lh] = w;               // Q = W = sqrtm·V
            Pw[i * LDSD + lh] = w * ev;          // P = W·diag(log λ)
        }
    }
    __syncthreads();
    mmb_nt_g(Pw, Qw, Tbuf + b * 1024, t64);      // T = W·diag·W^T
}

// fused: reduce part2 -> meanT (LDS only) -> wave-0 exp-map update -> bary
__global__ void __launch_bounds__(256) k_meanT_update(const float* part2, const int* labels, int B,
                                                      const float* sqrtm, const float* invsqrtm,
                                                      const float* bary0, float* bary) {
    __shared__ __align__(16) float P[MAT], Q[MAT];
    __shared__ int sc[4];
    int c = blockIdx.x, tid = threadIdx.x;
    int cnt = 0;
    for (int b = tid; b < B; b += 256) cnt += (labels[b] == c) ? 1 : 0;
#pragma unroll
    for (int off = 32; off > 0; off >>= 1) cnt += __shfl_down(cnt, off);
    if ((tid & 63) == 0) sc[tid >> 6] = cnt;
    __syncthreads();
    int total = sc[0] + sc[1] + sc[2] + sc[3];
    float acc[4] = {0.f, 0.f, 0.f, 0.f};
    for (int k = 0; k < NPART; ++k) {
#pragma unroll
        for (int e = 0; e < 4; ++e) acc[e] += part2[(k * NC + c) * 1024 + tid + 256 * e];
    }
    float inv = 1.f / (float)total;
#pragma unroll
    for (int e = 0; e < 4; ++e) {
        int idx = tid + 256 * e;
        P[(idx >> 5) * LDSD + (idx & 31)] = acc[e] * inv;   // meanT tile (LDS only)
    }
    __syncthreads();
    if (tid < 64) {
        int half = tid >> 5, lh = tid & 31;
        g2l<64>(invsqrtm + c * 1024, Q, tid);
        mmb_nn(Q, P, P, tid);                    // P = S·meanT
        mmb_nn(P, Q, Q, tid);                    // Q = N
        g2l<64>(sqrtm + c * 1024, P, tid);
        float z_[32];
        if (half == 0) {
#pragma unroll
            for (int r = 0; r < 32; ++r) {
                int i = r ^ lh;
                z_[r] = 0.5f * (Q[i * LDSD + lh] + Q[lh * LDSD + i]);
            }
        } else {
#pragma unroll
            for (int r = 0; r < 32; ++r) z_[r] = P[(r ^ lh) * LDSD + lh];  // W0 = sqrtm col
        }
        rjacobi_split<5>(z_, half, lh);
        float lam = __shfl(z_[0], lh, 64);
        // faithful quirk: clamp eigenvalues to >= 1e-10 BEFORE exp
        float ev = expf(fmaxf(lam, EV_EPS));
        if (half == 1) {
#pragma unroll
            for (int r = 0; r < 32; ++r) {
                float w = z_[r];
                int i = r ^ lh;
                Q[i * LDSD + lh] = w;                // Q = W
                P[i * LDSD + lh] = w * ev;           // P = W·diag(exp λ)
            }
        }
        // newbary tile = P·Q^T per lane; err vs bary0; select; write
        int j2 = (tid & 15) * 2, i0 = (tid >> 4) * 8;
        float2 ac[8];
#pragma unroll
        for (int r = 0; r < 8; ++r) { ac[r].x = 0.f; ac[r].y = 0.f; }
#pragma unroll
        for (int l = 0; l < 32; l += 2) {
            float2 b0 = *(const float2*)&Q[j2 * LDSD + l];
            float2 b1 = *(const float2*)&Q[(j2 + 1) * LDSD + l];
#pragma unroll
            for (int r = 0; r < 8; ++r) {
                float2 a = *(const float2*)&P[(i0 + r) * LDSD + l];
                ac[r].x = fmaf(a.x, b0.x, fmaf(a.y, b0.y, ac[r].x));
                ac[r].y = fmaf(a.x, b1.x, fmaf(a.y, b1.y, ac[r].y));
            }
        }
        float2 bv[8];
        float loc = 0.f;
#pragma unroll
        for (int r = 0; r < 8; ++r) {
            bv[r] = *(const float2*)&bary0[c * 1024 + (i0 + r) * 32 + j2];
            float dx = ac[r].x - bv[r].x, dy = ac[r].y - bv[r].y;
            loc += dx * dx + dy * dy;
        }
#pragma unroll
        for (int off = 32; off > 0; off >>= 1) loc += __shfl_down(loc, off);
        float err2 = __shfl(loc, 0);
        bool keep0 = (err2 < 1e-8f);  // CONV_TOL^2
#pragma unroll
        for (int r = 0; r < 8; ++r) {
            float2 w = keep0 ? bv[r] : ac[r];
            *(float2*)&bary[c * 1024 + (i0 + r) * 32 + j2] = w;
        }
    }
}

// pairdist: barriered Cholesky (256 threads) + barrier-free per-wave class loop
// with sched_barrier(0) fences to stop cross-phase load hoisting (round-11/12 spill fix)
__global__ void __launch_bounds__(256) k_pairdist(const float* X, const float* bary, float* D) {
    __shared__ __align__(16) float WA[MAT];        // X -> L -> Wt
    __shared__ __align__(16) float BC[4][MAT];     // per-wave class buffer
    int tid = threadIdx.x, wv = tid >> 6, t64 = tid & 63;
    int half = t64 >> 5, lh = tid & 31;
    int b = blockIdx.x;
    g2l<256>(X + b * 1024, WA, tid);
    __syncthreads();
    if (tid < 32) WA[tid * LDSD + tid] += 1e-3f;   // CHOL_EPS
    __syncthreads();
    // right-looking Cholesky (lower triangle), 256 threads on trailing updates
    for (int k = 0; k < 32; ++k) {
        if (tid == 0) WA[k * LDSD + k] = sqrtf(WA[k * LDSD + k]);
        __syncthreads();
        float invd = fast_rcp(WA[k * LDSD + k]);
        if (tid > k && tid < 32) WA[tid * LDSD + k] *= invd;
        __syncthreads();
        for (int idx = tid; idx < 1024; idx += 256) {
            int i = idx >> 5, j = idx & 31;
            if (i > k && j > k && j <= i) WA[i * LDSD + j] -= WA[i * LDSD + k] * WA[j * LDSD + k];
        }
        __syncthreads();
    }
    // forward substitution: lane j computes column j of W = L^{-1} in registers,
    // then writes row j of Wt = L^{-T} (reads precede writes in wave program order)
    if (tid < 32) {
        const int j = tid;
        float w[32];
#pragma unroll
        for (int i = 0; i < 32; ++i) {
            float acc = (i == j) ? 1.f : 0.f;
#pragma unroll
            for (int k = 0; k < 32; ++k) {
                if (k < i) acc = fmaf(-WA[i * LDSD + k], w[k], acc);
            }
            float val = acc * fast_rcp(WA[i * LDSD + i]);
            w[i] = (i < j) ? 0.f : val;
        }
#pragma unroll
        for (int i = 0; i < 32; ++i) WA[j * LDSD + i] = w[i];   // Wt row j
    }
    __syncthreads();                               // publish Wt to all waves
    // per-wave class loop: no block barriers (Bw wave-private, WA read-only).
    // sched_barrier(0) at phase edges pins scheduling -> no 128-reg WA-load hoist.
    float* Bw = BC[wv];
    float m_[32];
#pragma unroll 1
    for (int h = 0; h < 2; ++h) {
        int c = 2 * wv + h;
        g2l<64>(bary + c * 1024, Bw, t64);
        SCHED_FENCE();
        mmb_nn(WA, Bw, Bw, t64);              // Y = Wt·bary  (in-place, wave-private)
        SCHED_FENCE();
        mmb_nn(Bw, WA, Bw, t64);              // M = Y·Wt     (in-place, wave-private)
        SCHED_FENCE();
        if (half == h) {
#pragma unroll
            for (int r = 0; r < 32; ++r) {
                int i = r ^ lh;
                int hi = i > lh ? i : lh, lo = i > lh ? lh : i;  // eigvalsh UPLO='L'
                m_[r] = Bw[hi * LDSD + lo];
            }
        }
        SCHED_FENCE();
    }
    rjacobi_fixed(m_, 2);
    float lg = logf(fmaxf(m_[0], EV_EPS));
    float d2 = lg * lg;
#pragma unroll
    for (int off = 16; off > 0; off >>= 1) d2 += __shfl_xor(d2, off, 32);
    if (lh == 0) D[b * NC + 2 * wv + half] = sqrtf(d2);
}

__global__ void k_loss(const float* out, const int* labels, const float* D, int B, float* res) {
    __shared__ float sI[256], sD[256], sC[256];
    int tid = threadIdx.x;
    float aI = 0.f, aD = 0.f, aC = 0.f;
    for (int b = tid; b < B; b += 256) {
        int lb = labels[b];
        const float* ob = out + b * NC;
        float m = ob[0];
#pragma unroll
        for (int j = 1; j < NC; ++j) m = fmaxf(m, ob[j]);
        float se = 0.f;
#pragma unroll
        for (int j = 0; j < NC; ++j) se += expf(ob[j] - m);
        aC += m + logf(se) - ob[lb];
        const float* db = D + b * NC;
        float s = 0.f;
#pragma unroll
        for (int j = 0; j < NC; ++j) s += db[j];
        aI += db[lb];
        aD += s - db[lb];
    }
    sI[tid] = aI; sD[tid] = aD; sC[tid] = aC;
    __syncthreads();
    for (int off = 128; off > 0; off >>= 1) {
        if (tid < off) { sI[tid] += sI[tid + off]; sD[tid] += sD[tid + off]; sC[tid] += sC[tid + off]; }
        __syncthreads();
    }
    if (tid == 0) {
        float intra = 0.001f * sI[0] / (float)B;
        float disp = sD[0] / (float)(B * (NC - 1));
        float ce = sC[0] / (float)B;
        res[0] = intra - 0.001f * disp + ce;
    }
}

extern "C" void kernel_launch(void* const* d_in, const int* in_sizes, int n_in,
                              void* d_out, int out_size, void* d_ws, size_t ws_size,
                              hipStream_t stream) {
    const float* X = (const float*)d_in[0];
    const float* out = (const float*)d_in[1];
    const int* labels = (const int*)d_in[2];
    int B = in_sizes[2];

    float* ws = (float*)d_ws;
    float* bary0    = ws;                 // 8192
    float* sqrtm    = ws + 8192;          // 8192
    float* invsqrtm = ws + 16384;         // 8192
    float* bary     = ws + 32768;         // 8192
    float* D        = ws + 40960;         // B*8 = 16384
    float* big      = ws + 65536;         // B*1024 floats (partials, then T)
    float* part2    = ws + 65536 + (size_t)B * 1024;  // NPART*NC*1024 floats

    k_accum_part<<<NPART, 256, 0, stream>>>(X, labels, B, big);
    k_bary0_eig<<<NC, 256, 0, stream>>>(big, labels, B, bary0, sqrtm, invsqrtm);
    k_tangent<<<B / 4, 256, 0, stream>>>(X, labels, sqrtm, invsqrtm, big);
    k_accum_part<<<NPART, 256, 0, stream>>>(big, labels, B, part2);
    k_meanT_update<<<NC, 256, 0, stream>>>(part2, labels, B, sqrtm, invsqrtm, bary0, bary);
    k_pairdist<<<B, 256, 0, stream>>>(X, bary, D);
    k_loss<<<1, 256, 0, stream>>>(out, labels, D, B, (float*)d_out);
}

// Round 14
// 1004.581 us; speedup vs baseline: 2.3318x; 1.1693x over previous
//
#include <hip/hip_runtime.h>
#include <math.h>

#define NC 8
#define NDIM 32
#define LDSD 34            // stride 34: rows 8B-aligned (float2); col access 2-way bank alias (free)
#define MAT (NDIM * LDSD)  // 1088 floats per LDS matrix
#define EV_EPS 1e-10f
#define NPART 64

#if __has_builtin(__builtin_amdgcn_rcpf)
__device__ inline float fast_rcp(float x) { return __builtin_amdgcn_rcpf(x); }
#else
__device__ inline float fast_rcp(float x) { return 1.f / x; }
#endif
#if __has_builtin(__builtin_amdgcn_rsqf)
__device__ inline float fast_rsq(float x) { return __builtin_amdgcn_rsqf(x); }
#else
__device__ inline float fast_rsq(float x) { return 1.f / sqrtf(x); }
#endif

#define SCHED_FENCE() __builtin_amdgcn_sched_barrier(0)

// ---------- 32x32 LDS helpers ----------
template <int NT>
__device__ inline void g2l(const float* g, float* l, int t) {
    for (int idx2 = t; idx2 < 512; idx2 += NT) {
        int i = idx2 >> 4, jp = idx2 & 15;
        *(float2*)&l[i * LDSD + 2 * jp] = *(const float2*)&g[i * 32 + 2 * jp];
    }
}

// ---------- register-tiled LDS matmuls (one wave; 8-row x 2-col tile/lane; t = 0..63) ----------
// C = A * B.  Wave-private safe for ANY aliasing (C==A or C==B): all read
// instructions precede all stores in the wave's in-order instruction stream.
__device__ inline void mmb_nn(const float* A, const float* B, float* C, int t) {
    int j2 = (t & 15) * 2;
    int i0 = (t >> 4) * 8;
    float2 ac[8];
#pragma unroll
    for (int r = 0; r < 8; ++r) { ac[r].x = 0.f; ac[r].y = 0.f; }
#pragma unroll
    for (int k = 0; k < 32; k += 2) {
        float2 b0 = *(const float2*)&B[k * LDSD + j2];
        float2 b1 = *(const float2*)&B[(k + 1) * LDSD + j2];
#pragma unroll
        for (int r = 0; r < 8; ++r) {
            float2 a = *(const float2*)&A[(i0 + r) * LDSD + k];
            ac[r].x = fmaf(a.x, b0.x, fmaf(a.y, b1.x, ac[r].x));
            ac[r].y = fmaf(a.x, b0.y, fmaf(a.y, b1.y, ac[r].y));
        }
    }
#pragma unroll
    for (int r = 0; r < 8; ++r) *(float2*)&C[(i0 + r) * LDSD + j2] = ac[r];
}
// gC(global, stride 32) = A * B^T
__device__ inline void mmb_nt_g(const float* A, const float* B, float* gC, int t) {
    int j2 = (t & 15) * 2;
    int i0 = (t >> 4) * 8;
    float2 ac[8];
#pragma unroll
    for (int r = 0; r < 8; ++r) { ac[r].x = 0.f; ac[r].y = 0.f; }
#pragma unroll
    for (int l = 0; l < 32; l += 2) {
        float2 b0 = *(const float2*)&B[j2 * LDSD + l];
        float2 b1 = *(const float2*)&B[(j2 + 1) * LDSD + l];
#pragma unroll
        for (int r = 0; r < 8; ++r) {
            float2 a = *(const float2*)&A[(i0 + r) * LDSD + l];
            ac[r].x = fmaf(a.x, b0.x, fmaf(a.y, b0.y, ac[r].x));
            ac[r].y = fmaf(a.x, b1.x, fmaf(a.y, b1.y, ac[r].y));
        }
    }
#pragma unroll
    for (int r = 0; r < 8; ++r) *(float2*)&gC[(i0 + r) * 32 + j2] = ac[r];
}

// ---------- register-resident XOR-ordered Jacobi, eigenvalues only, fixed sweeps ----------
// Lane lh holds column lh skewed: m_[r] = M[r^lh][lh]; diag = m_[0].
__device__ inline void rjacobi_fixed(float* m_, int nsweep) {
    for (int sweep = 0; sweep < nsweep; ++sweep) {
#pragma unroll
        for (int mm = 1; mm < 32; ++mm) {
            float app = m_[0];
            float aqq = __shfl_xor(app, mm, 32);
            float apq = m_[mm];
            float apqc = __builtin_copysignf(fmaxf(fabsf(apq), 1e-36f), apq);
            float tau = (aqq - app) * 0.5f * fast_rcp(apqc);
            float den = fabsf(tau) + sqrtf(fmaf(tau, tau, 1.f));
            float t = __builtin_copysignf(fast_rcp(den), tau);
            t = (fabsf(apq) > 1e-36f) ? t : 0.f;
            float cc = fast_rsq(fmaf(t, t, 1.f));
            float ss = t * cc;
#pragma unroll
            for (int r = 0; r < 32; ++r) {
                if (r < (r ^ mm)) {
                    const int r2 = r ^ mm;
                    float ti = __shfl_xor(t, r, 32);
                    float ci = fast_rsq(fmaf(ti, ti, 1.f));
                    float si = ti * ci;
                    float x = m_[r], y = m_[r2];
                    m_[r]  = ci * x - si * y;
                    m_[r2] = ci * y + si * x;
                }
            }
            float o[32];
#pragma unroll
            for (int u = 0; u < 32; ++u) o[u] = __shfl_xor(m_[u ^ mm], mm, 32);
#pragma unroll
            for (int u = 0; u < 32; ++u) m_[u] = fmaf(cc, m_[u], -ss * o[u]);
        }
    }
}

// ---------- split-role register Jacobi: half 0 solves M, half 1 accumulates W·V ----------
template <int NSWEEP>
__device__ inline void rjacobi_split(float* z_, int half, int lh) {
    for (int sweep = 0; sweep < NSWEEP; ++sweep) {
#pragma unroll
        for (int mm = 1; mm < 32; ++mm) {
            float app = z_[0];
            float aqq = __shfl_xor(app, mm, 32);
            float apq = z_[mm];
            float apqc = __builtin_copysignf(fmaxf(fabsf(apq), 1e-36f), apq);
            float tau = (aqq - app) * 0.5f * fast_rcp(apqc);
            float den = fabsf(tau) + sqrtf(fmaf(tau, tau, 1.f));
            float t = __builtin_copysignf(fast_rcp(den), tau);
            t = (fabsf(apq) > 1e-36f) ? t : 0.f;
            t = __shfl(t, lh, 64);               // half 1 inherits half 0's t (wave-local)
            float cc = fast_rsq(fmaf(t, t, 1.f));
            float ss = t * cc;
            if (half == 0) {                     // row rotations on M only (t-refetch)
#pragma unroll
                for (int r = 0; r < 32; ++r) {
                    if (r < (r ^ mm)) {
                        const int r2 = r ^ mm;
                        float ti = __shfl_xor(t, r, 32);
                        float ci = fast_rsq(fmaf(ti, ti, 1.f));
                        float si = ti * ci;
                        float x = z_[r], y = z_[r2];
                        z_[r]  = ci * x - si * y;
                        z_[r2] = ci * y + si * x;
                    }
                }
            }
            float o[32];
#pragma unroll
            for (int u = 0; u < 32; ++u) o[u] = __shfl_xor(z_[u ^ mm], mm, 32);
#pragma unroll
            for (int u = 0; u < 32; ++u) z_[u] = fmaf(cc, z_[u], -ss * o[u]);
        }
    }
}

// ---------- kernels ----------
__global__ void __launch_bounds__(256) k_accum_part(const float* src, const int* labels, int B, float* part) {
    int blk = blockIdx.x, tid = threadIdx.x;
    int chunk = (B + NPART - 1) / NPART;
    int b0 = blk * chunk, b1 = b0 + chunk < B ? b0 + chunk : B;
    float acc[NC][4];
#pragma unroll
    for (int c = 0; c < NC; ++c)
#pragma unroll
        for (int e = 0; e < 4; ++e) acc[c][e] = 0.f;
    for (int b = b0; b < b1; ++b) {
        int lb = labels[b];
        float x[4];
#pragma unroll
        for (int e = 0; e < 4; ++e) x[e] = src[b * 1024 + tid + 256 * e];
#pragma unroll
        for (int c = 0; c < NC; ++c) {
            if (lb == c) {
#pragma unroll
                for (int e = 0; e < 4; ++e) acc[c][e] += x[e];
            }
        }
    }
#pragma unroll
    for (int c = 0; c < NC; ++c)
#pragma unroll
        for (int e = 0; e < 4; ++e) part[(blk * NC + c) * 1024 + tid + 256 * e] = acc[c][e];
}

// fused: reduce partials -> bary0 (global + LDS tile) -> wave-0 eigen -> sqrtm/invsqrtm
__global__ void __launch_bounds__(256) k_bary0_eig(const float* part, const int* labels, int B,
                                                   float* bary0, float* sqrtm, float* invsqrtm) {
    __shared__ __align__(16) float P[MAT], Q[MAT];
    __shared__ int sc[4];
    int c = blockIdx.x, tid = threadIdx.x;
    int cnt = 0;
    for (int b = tid; b < B; b += 256) cnt += (labels[b] == c) ? 1 : 0;
#pragma unroll
    for (int off = 32; off > 0; off >>= 1) cnt += __shfl_down(cnt, off);
    if ((tid & 63) == 0) sc[tid >> 6] = cnt;
    __syncthreads();
    int total = sc[0] + sc[1] + sc[2] + sc[3];
    float acc[4] = {0.f, 0.f, 0.f, 0.f};
    for (int k = 0; k < NPART; ++k) {
#pragma unroll
        for (int e = 0; e < 4; ++e) acc[e] += part[(k * NC + c) * 1024 + tid + 256 * e];
    }
    float inv = 1.f / (float)total;
#pragma unroll
    for (int e = 0; e < 4; ++e) {
        int idx = tid + 256 * e;
        float v = acc[e] * inv;
        P[(idx >> 5) * LDSD + (idx & 31)] = v;
        bary0[c * 1024 + idx] = v;
    }
    __syncthreads();
    if (tid < 64) {
        int half = tid >> 5, lh = tid & 31;
        float z_[32];
        if (half == 0) {
#pragma unroll
            for (int r = 0; r < 32; ++r) {
                int i = r ^ lh;
                z_[r] = 0.5f * (P[i * LDSD + lh] + P[lh * LDSD + i]);
            }
        } else {
#pragma unroll
            for (int r = 0; r < 32; ++r) z_[r] = (r == 0) ? 1.f : 0.f;   // V0 = I col
        }
        rjacobi_split<3>(z_, half, lh);
        float lam = __shfl(z_[0], lh, 64);
        float esq = sqrtf(fmaxf(lam, 0.f));
        float eisq = fast_rsq(fmaxf(lam, 1e-30f));
        if (half == 1) {
#pragma unroll
            for (int r = 0; r < 32; ++r) {
                int i = r ^ lh;
                Q[i * LDSD + lh] = z_[r];            // Q = V
                P[i * LDSD + lh] = z_[r] * esq;      // P = V·diag(sqrt λ)
            }
        }
        mmb_nt_g(P, Q, sqrtm + c * 1024, tid);       // sqrtm = V diag V^T
        if (half == 1) {
#pragma unroll
            for (int r = 0; r < 32; ++r) P[(r ^ lh) * LDSD + lh] = z_[r] * eisq;
        }
        mmb_nt_g(P, Q, invsqrtm + c * 1024, tid);    // invsqrtm = V diag^-1 V^T
    }
}

// tangent: 4 samples per 256-thread block (per-wave P,Q); split-role wave; 2 sweeps.
// All LDS is wave-private -> block barriers replaced by sched fences (spill guard).
__global__ void __launch_bounds__(256) k_tangent(const float* X, const int* labels, const float* sqrtm,
                                                 const float* invsqrtm, float* Tbuf) {
    __shared__ __align__(16) float P[4][MAT], Q[4][MAT];   // 34816 B, per-wave
    int tid = threadIdx.x, wv = tid >> 6, t64 = tid & 63;
    int half = t64 >> 5, lh = tid & 31;
    int b = blockIdx.x * 4 + wv;
    int lb = labels[b];
    float* Pw = P[wv];
    float* Qw = Q[wv];
    g2l<64>(X + b * 1024, Pw, t64);
    g2l<64>(invsqrtm + lb * 1024, Qw, t64);
    SCHED_FENCE();
    mmb_nn(Qw, Pw, Pw, t64);                    // P = S·X      (in-place, wave-private)
    SCHED_FENCE();
    mmb_nn(Pw, Qw, Qw, t64);                    // Q = (S·X)·S = M
    SCHED_FENCE();
    g2l<64>(sqrtm + lb * 1024, Pw, t64);        // P = sqrtm
    SCHED_FENCE();
    float z_[32];
    if (half == 0) {
#pragma unroll
        for (int r = 0; r < 32; ++r) {
            int i = r ^ lh;
            z_[r] = 0.5f * (Qw[i * LDSD + lh] + Qw[lh * LDSD + i]);   // symmetrized M
        }
    } else {
#pragma unroll
        for (int r = 0; r < 32; ++r) z_[r] = Pw[(r ^ lh) * LDSD + lh];  // W0 = sqrtm col (skew)
    }
    SCHED_FENCE();
    rjacobi_split<2>(z_, half, lh);
    float lam = __shfl(z_[0], lh, 64);          // wave-local broadcast of half-0 eigenvalue
    float ev = logf(fmaxf(lam, EV_EPS));
    SCHED_FENCE();                               // extraction reads precede stores (in-order wave)
    if (half == 1) {
#pragma unroll
        for (int r = 0; r < 32; ++r) {
            float w = z_[r];
            int i = r ^ lh;
            Qw[i * LDSD + lh] = w;               // Q = W = sqrtm·V
            Pw[i * LDSD + lh] = w * ev;          // P = W·diag(log λ)
        }
    }
    SCHED_FENCE();
    mmb_nt_g(Pw, Qw, Tbuf + b * 1024, t64);      // T = W·diag·W^T
}

// fused: reduce part2 -> meanT (LDS only) -> wave-0 exp-map update -> bary
__global__ void __launch_bounds__(256) k_meanT_update(const float* part2, const int* labels, int B,
                                                      const float* sqrtm, const float* invsqrtm,
                                                      const float* bary0, float* bary) {
    __shared__ __align__(16) float P[MAT], Q[MAT];
    __shared__ int sc[4];
    int c = blockIdx.x, tid = threadIdx.x;
    int cnt = 0;
    for (int b = tid; b < B; b += 256) cnt += (labels[b] == c) ? 1 : 0;
#pragma unroll
    for (int off = 32; off > 0; off >>= 1) cnt += __shfl_down(cnt, off);
    if ((tid & 63) == 0) sc[tid >> 6] = cnt;
    __syncthreads();
    int total = sc[0] + sc[1] + sc[2] + sc[3];
    float acc[4] = {0.f, 0.f, 0.f, 0.f};
    for (int k = 0; k < NPART; ++k) {
#pragma unroll
        for (int e = 0; e < 4; ++e) acc[e] += part2[(k * NC + c) * 1024 + tid + 256 * e];
    }
    float inv = 1.f / (float)total;
#pragma unroll
    for (int e = 0; e < 4; ++e) {
        int idx = tid + 256 * e;
        P[(idx >> 5) * LDSD + (idx & 31)] = acc[e] * inv;   // meanT tile (LDS only)
    }
    __syncthreads();
    if (tid < 64) {
        int half = tid >> 5, lh = tid & 31;
        g2l<64>(invsqrtm + c * 1024, Q, tid);
        mmb_nn(Q, P, P, tid);                    // P = S·meanT
        mmb_nn(P, Q, Q, tid);                    // Q = N
        g2l<64>(sqrtm + c * 1024, P, tid);
        float z_[32];
        if (half == 0) {
#pragma unroll
            for (int r = 0; r < 32; ++r) {
                int i = r ^ lh;
                z_[r] = 0.5f * (Q[i * LDSD + lh] + Q[lh * LDSD + i]);
            }
        } else {
#pragma unroll
            for (int r = 0; r < 32; ++r) z_[r] = P[(r ^ lh) * LDSD + lh];  // W0 = sqrtm col
        }
        rjacobi_split<3>(z_, half, lh);
        float lam = __shfl(z_[0], lh, 64);
        // faithful quirk: clamp eigenvalues to >= 1e-10 BEFORE exp
        float ev = expf(fmaxf(lam, EV_EPS));
        if (half == 1) {
#pragma unroll
            for (int r = 0; r < 32; ++r) {
                float w = z_[r];
                int i = r ^ lh;
                Q[i * LDSD + lh] = w;                // Q = W
                P[i * LDSD + lh] = w * ev;           // P = W·diag(exp λ)
            }
        }
        // newbary tile = P·Q^T per lane; err vs bary0; select; write
        int j2 = (tid & 15) * 2, i0 = (tid >> 4) * 8;
        float2 ac[8];
#pragma unroll
        for (int r = 0; r < 8; ++r) { ac[r].x = 0.f; ac[r].y = 0.f; }
#pragma unroll
        for (int l = 0; l < 32; l += 2) {
            float2 b0 = *(const float2*)&Q[j2 * LDSD + l];
            float2 b1 = *(const float2*)&Q[(j2 + 1) * LDSD + l];
#pragma unroll
            for (int r = 0; r < 8; ++r) {
                float2 a = *(const float2*)&P[(i0 + r) * LDSD + l];
                ac[r].x = fmaf(a.x, b0.x, fmaf(a.y, b0.y, ac[r].x));
                ac[r].y = fmaf(a.x, b1.x, fmaf(a.y, b1.y, ac[r].y));
            }
        }
        float2 bv[8];
        float loc = 0.f;
#pragma unroll
        for (int r = 0; r < 8; ++r) {
            bv[r] = *(const float2*)&bary0[c * 1024 + (i0 + r) * 32 + j2];
            float dx = ac[r].x - bv[r].x, dy = ac[r].y - bv[r].y;
            loc += dx * dx + dy * dy;
        }
#pragma unroll
        for (int off = 32; off > 0; off >>= 1) loc += __shfl_down(loc, off);
        float err2 = __shfl(loc, 0);
        bool keep0 = (err2 < 1e-8f);  // CONV_TOL^2
#pragma unroll
        for (int r = 0; r < 8; ++r) {
            float2 w = keep0 ? bv[r] : ac[r];
            *(float2*)&bary[c * 1024 + (i0 + r) * 32 + j2] = w;
        }
    }
}

// pairdist: barriered Cholesky (256 threads) + barrier-free per-wave class loop
// with sched_barrier(0) fences (round-13 proven form, VGPR 120)
__global__ void __launch_bounds__(256) k_pairdist(const float* X, const float* bary, float* D) {
    __shared__ __align__(16) float WA[MAT];        // X -> L -> Wt
    __shared__ __align__(16) float BC[4][MAT];     // per-wave class buffer
    int tid = threadIdx.x, wv = tid >> 6, t64 = tid & 63;
    int half = t64 >> 5, lh = tid & 31;
    int b = blockIdx.x;
    g2l<256>(X + b * 1024, WA, tid);
    __syncthreads();
    if (tid < 32) WA[tid * LDSD + tid] += 1e-3f;   // CHOL_EPS
    __syncthreads();
    // right-looking Cholesky (lower triangle), 256 threads on trailing updates
    for (int k = 0; k < 32; ++k) {
        if (tid == 0) WA[k * LDSD + k] = sqrtf(WA[k * LDSD + k]);
        __syncthreads();
        float invd = fast_rcp(WA[k * LDSD + k]);
        if (tid > k && tid < 32) WA[tid * LDSD + k] *= invd;
        __syncthreads();
        for (int idx = tid; idx < 1024; idx += 256) {
            int i = idx >> 5, j = idx & 31;
            if (i > k && j > k && j <= i) WA[i * LDSD + j] -= WA[i * LDSD + k] * WA[j * LDSD + k];
        }
        __syncthreads();
    }
    // forward substitution: lane j computes column j of W = L^{-1} in registers,
    // then writes row j of Wt = L^{-T} (reads precede writes in wave program order)
    if (tid < 32) {
        const int j = tid;
        float w[32];
#pragma unroll
        for (int i = 0; i < 32; ++i) {
            float acc = (i == j) ? 1.f : 0.f;
#pragma unroll
            for (int k = 0; k < 32; ++k) {
                if (k < i) acc = fmaf(-WA[i * LDSD + k], w[k], acc);
            }
            float val = acc * fast_rcp(WA[i * LDSD + i]);
            w[i] = (i < j) ? 0.f : val;
        }
#pragma unroll
        for (int i = 0; i < 32; ++i) WA[j * LDSD + i] = w[i];   // Wt row j
    }
    __syncthreads();                               // publish Wt to all waves
    // per-wave class loop: no block barriers (Bw wave-private, WA read-only).
    // sched_barrier(0) at phase edges pins scheduling -> no cross-phase load hoist.
    float* Bw = BC[wv];
    float m_[32];
#pragma unroll 1
    for (int h = 0; h < 2; ++h) {
        int c = 2 * wv + h;
        g2l<64>(bary + c * 1024, Bw, t64);
        SCHED_FENCE();
        mmb_nn(WA, Bw, Bw, t64);              // Y = Wt·bary  (in-place, wave-private)
        SCHED_FENCE();
        mmb_nn(Bw, WA, Bw, t64);              // M = Y·Wt     (in-place, wave-private)
        SCHED_FENCE();
        if (half == h) {
#pragma unroll
            for (int r = 0; r < 32; ++r) {
                int i = r ^ lh;
                int hi = i > lh ? i : lh, lo = i > lh ? lh : i;  // eigvalsh UPLO='L'
                m_[r] = Bw[hi * LDSD + lo];
            }
        }
        SCHED_FENCE();
    }
    rjacobi_fixed(m_, 2);
    float lg = logf(fmaxf(m_[0], EV_EPS));
    float d2 = lg * lg;
#pragma unroll
    for (int off = 16; off > 0; off >>= 1) d2 += __shfl_xor(d2, off, 32);
    if (lh == 0) D[b * NC + 2 * wv + half] = sqrtf(d2);
}

__global__ void k_loss(const float* out, const int* labels, const float* D, int B, float* res) {
    __shared__ float sI[256], sD[256], sC[256];
    int tid = threadIdx.x;
    float aI = 0.f, aD = 0.f, aC = 0.f;
    for (int b = tid; b < B; b += 256) {
        int lb = labels[b];
        const float* ob = out + b * NC;
        float m = ob[0];
#pragma unroll
        for (int j = 1; j < NC; ++j) m = fmaxf(m, ob[j]);
        float se = 0.f;
#pragma unroll
        for (int j = 0; j < NC; ++j) se += expf(ob[j] - m);
        aC += m + logf(se) - ob[lb];
        const float* db = D + b * NC;
        float s = 0.f;
#pragma unroll
        for (int j = 0; j < NC; ++j) s += db[j];
        aI += db[lb];
        aD += s - db[lb];
    }
    sI[tid] = aI; sD[tid] = aD; sC[tid] = aC;
    __syncthreads();
    for (int off = 128; off > 0; off >>= 1) {
        if (tid < off) { sI[tid] += sI[tid + off]; sD[tid] += sD[tid + off]; sC[tid] += sC[tid + off]; }
        __syncthreads();
    }
    if (tid == 0) {
        float intra = 0.001f * sI[0] / (float)B;
        float disp = sD[0] / (float)(B * (NC - 1));
        float ce = sC[0] / (float)B;
        res[0] = intra - 0.001f * disp + ce;
    }
}

extern "C" void kernel_launch(void* const* d_in, const int* in_sizes, int n_in,
                              void* d_out, int out_size, void* d_ws, size_t ws_size,
                              hipStream_t stream) {
    const float* X = (const float*)d_in[0];
    const float* out = (const float*)d_in[1];
    const int* labels = (const int*)d_in[2];
    int B = in_sizes[2];

    float* ws = (float*)d_ws;
    float* bary0    = ws;                 // 8192
    float* sqrtm    = ws + 8192;          // 8192
    float* invsqrtm = ws + 16384;         // 8192
    float* bary     = ws + 32768;         // 8192
    float* D        = ws + 40960;         // B*8 = 16384
    float* big      = ws + 65536;         // B*1024 floats (partials, then T)
    float* part2    = ws + 65536 + (size_t)B * 1024;  // NPART*NC*1024 floats

    k_accum_part<<<NPART, 256, 0, stream>>>(X, labels, B, big);
    k_bary0_eig<<<NC, 256, 0, stream>>>(big, labels, B, bary0, sqrtm, invsqrtm);
    k_tangent<<<B / 4, 256, 0, stream>>>(X, labels, sqrtm, invsqrtm, big);
    k_accum_part<<<NPART, 256, 0, stream>>>(big, labels, B, part2);
    k_meanT_update<<<NC, 256, 0, stream>>>(part2, labels, B, sqrtm, invsqrtm, bary0, bary);
    k_pairdist<<<B, 256, 0, stream>>>(X, bary, D);
    k_loss<<<1, 256, 0, stream>>>(out, labels, D, B, (float*)d_out);
}

// Round 15
// 812.497 us; speedup vs baseline: 2.8831x; 1.2364x over previous
//
#include <hip/hip_runtime.h>
#include <math.h>

#define NC 8
#define NDIM 32
#define LDSD 34            // stride 34: rows 8B-aligned (float2); col access 2-way bank alias (free)
#define MAT (NDIM * LDSD)  // 1088 floats per LDS matrix
#define EV_EPS 1e-10f
#define NPART 64

#if __has_builtin(__builtin_amdgcn_rcpf)
__device__ inline float fast_rcp(float x) { return __builtin_amdgcn_rcpf(x); }
#else
__device__ inline float fast_rcp(float x) { return 1.f / x; }
#endif
#if __has_builtin(__builtin_amdgcn_rsqf)
__device__ inline float fast_rsq(float x) { return __builtin_amdgcn_rsqf(x); }
#else
__device__ inline float fast_rsq(float x) { return 1.f / sqrtf(x); }
#endif

#define SCHED_FENCE() __builtin_amdgcn_sched_barrier(0)

// ---------- 32x32 LDS helpers ----------
template <int NT>
__device__ inline void g2l(const float* g, float* l, int t) {
    for (int idx2 = t; idx2 < 512; idx2 += NT) {
        int i = idx2 >> 4, jp = idx2 & 15;
        *(float2*)&l[i * LDSD + 2 * jp] = *(const float2*)&g[i * 32 + 2 * jp];
    }
}

// ---------- register-tiled LDS matmuls (one wave; 8-row x 2-col tile/lane; t = 0..63) ----------
// C = A * B.  Wave-private safe for ANY aliasing (C==A or C==B): all read
// instructions precede all stores in the wave's in-order instruction stream.
__device__ inline void mmb_nn(const float* A, const float* B, float* C, int t) {
    int j2 = (t & 15) * 2;
    int i0 = (t >> 4) * 8;
    float2 ac[8];
#pragma unroll
    for (int r = 0; r < 8; ++r) { ac[r].x = 0.f; ac[r].y = 0.f; }
#pragma unroll
    for (int k = 0; k < 32; k += 2) {
        float2 b0 = *(const float2*)&B[k * LDSD + j2];
        float2 b1 = *(const float2*)&B[(k + 1) * LDSD + j2];
#pragma unroll
        for (int r = 0; r < 8; ++r) {
            float2 a = *(const float2*)&A[(i0 + r) * LDSD + k];
            ac[r].x = fmaf(a.x, b0.x, fmaf(a.y, b1.x, ac[r].x));
            ac[r].y = fmaf(a.x, b0.y, fmaf(a.y, b1.y, ac[r].y));
        }
    }
#pragma unroll
    for (int r = 0; r < 8; ++r) *(float2*)&C[(i0 + r) * LDSD + j2] = ac[r];
}
// gC(global, stride 32) = A * B^T
__device__ inline void mmb_nt_g(const float* A, const float* B, float* gC, int t) {
    int j2 = (t & 15) * 2;
    int i0 = (t >> 4) * 8;
    float2 ac[8];
#pragma unroll
    for (int r = 0; r < 8; ++r) { ac[r].x = 0.f; ac[r].y = 0.f; }
#pragma unroll
    for (int l = 0; l < 32; l += 2) {
        float2 b0 = *(const float2*)&B[j2 * LDSD + l];
        float2 b1 = *(const float2*)&B[(j2 + 1) * LDSD + l];
#pragma unroll
        for (int r = 0; r < 8; ++r) {
            float2 a = *(const float2*)&A[(i0 + r) * LDSD + l];
            ac[r].x = fmaf(a.x, b0.x, fmaf(a.y, b0.y, ac[r].x));
            ac[r].y = fmaf(a.x, b1.x, fmaf(a.y, b1.y, ac[r].y));
        }
    }
#pragma unroll
    for (int r = 0; r < 8; ++r) *(float2*)&gC[(i0 + r) * 32 + j2] = ac[r];
}

// ---------- register-resident XOR-ordered Jacobi, eigenvalues only, fixed sweeps ----------
// Lane lh holds column lh skewed: m_[r] = M[r^lh][lh]; diag = m_[0].
__device__ inline void rjacobi_fixed(float* m_, int nsweep) {
    for (int sweep = 0; sweep < nsweep; ++sweep) {
#pragma unroll
        for (int mm = 1; mm < 32; ++mm) {
            float app = m_[0];
            float aqq = __shfl_xor(app, mm, 32);
            float apq = m_[mm];
            float apqc = __builtin_copysignf(fmaxf(fabsf(apq), 1e-36f), apq);
            float tau = (aqq - app) * 0.5f * fast_rcp(apqc);
            float den = fabsf(tau) + sqrtf(fmaf(tau, tau, 1.f));
            float t = __builtin_copysignf(fast_rcp(den), tau);
            t = (fabsf(apq) > 1e-36f) ? t : 0.f;
            float cc = fast_rsq(fmaf(t, t, 1.f));
            float ss = t * cc;
#pragma unroll
            for (int r = 0; r < 32; ++r) {
                if (r < (r ^ mm)) {
                    const int r2 = r ^ mm;
                    float ti = __shfl_xor(t, r, 32);
                    float ci = fast_rsq(fmaf(ti, ti, 1.f));
                    float si = ti * ci;
                    float x = m_[r], y = m_[r2];
                    m_[r]  = ci * x - si * y;
                    m_[r2] = ci * y + si * x;
                }
            }
            float o[32];
#pragma unroll
            for (int u = 0; u < 32; ++u) o[u] = __shfl_xor(m_[u ^ mm], mm, 32);
#pragma unroll
            for (int u = 0; u < 32; ++u) m_[u] = fmaf(cc, m_[u], -ss * o[u]);
        }
    }
}

// ---------- split-role register Jacobi: half 0 solves M, half 1 accumulates W·V ----------
template <int NSWEEP>
__device__ inline void rjacobi_split(float* z_, int half, int lh) {
    for (int sweep = 0; sweep < NSWEEP; ++sweep) {
#pragma unroll
        for (int mm = 1; mm < 32; ++mm) {
            float app = z_[0];
            float aqq = __shfl_xor(app, mm, 32);
            float apq = z_[mm];
            float apqc = __builtin_copysignf(fmaxf(fabsf(apq), 1e-36f), apq);
            float tau = (aqq - app) * 0.5f * fast_rcp(apqc);
            float den = fabsf(tau) + sqrtf(fmaf(tau, tau, 1.f));
            float t = __builtin_copysignf(fast_rcp(den), tau);
            t = (fabsf(apq) > 1e-36f) ? t : 0.f;
            t = __shfl(t, lh, 64);               // half 1 inherits half 0's t (wave-local)
            float cc = fast_rsq(fmaf(t, t, 1.f));
            float ss = t * cc;
            if (half == 0) {                     // row rotations on M only (t-refetch)
#pragma unroll
                for (int r = 0; r < 32; ++r) {
                    if (r < (r ^ mm)) {
                        const int r2 = r ^ mm;
                        float ti = __shfl_xor(t, r, 32);
                        float ci = fast_rsq(fmaf(ti, ti, 1.f));
                        float si = ti * ci;
                        float x = z_[r], y = z_[r2];
                        z_[r]  = ci * x - si * y;
                        z_[r2] = ci * y + si * x;
                    }
                }
            }
            float o[32];
#pragma unroll
            for (int u = 0; u < 32; ++u) o[u] = __shfl_xor(z_[u ^ mm], mm, 32);
#pragma unroll
            for (int u = 0; u < 32; ++u) z_[u] = fmaf(cc, z_[u], -ss * o[u]);
        }
    }
}

// ---------- kernels ----------
__global__ void __launch_bounds__(256) k_accum_part(const float* src, const int* labels, int B, float* part) {
    int blk = blockIdx.x, tid = threadIdx.x;
    int chunk = (B + NPART - 1) / NPART;
    int b0 = blk * chunk, b1 = b0 + chunk < B ? b0 + chunk : B;
    float acc[NC][4];
#pragma unroll
    for (int c = 0; c < NC; ++c)
#pragma unroll
        for (int e = 0; e < 4; ++e) acc[c][e] = 0.f;
    for (int b = b0; b < b1; ++b) {
        int lb = labels[b];
        float x[4];
#pragma unroll
        for (int e = 0; e < 4; ++e) x[e] = src[b * 1024 + tid + 256 * e];
#pragma unroll
        for (int c = 0; c < NC; ++c) {
            if (lb == c) {
#pragma unroll
                for (int e = 0; e < 4; ++e) acc[c][e] += x[e];
            }
        }
    }
#pragma unroll
    for (int c = 0; c < NC; ++c)
#pragma unroll
        for (int e = 0; e < 4; ++e) part[(blk * NC + c) * 1024 + tid + 256 * e] = acc[c][e];
}

// fused: reduce partials -> bary0 (global + LDS tile) -> wave-0 eigen -> sqrtm/invsqrtm
__global__ void __launch_bounds__(256) k_bary0_eig(const float* part, const int* labels, int B,
                                                   float* bary0, float* sqrtm, float* invsqrtm) {
    __shared__ __align__(16) float P[MAT], Q[MAT];
    __shared__ int sc[4];
    int c = blockIdx.x, tid = threadIdx.x;
    int cnt = 0;
    for (int b = tid; b < B; b += 256) cnt += (labels[b] == c) ? 1 : 0;
#pragma unroll
    for (int off = 32; off > 0; off >>= 1) cnt += __shfl_down(cnt, off);
    if ((tid & 63) == 0) sc[tid >> 6] = cnt;
    __syncthreads();
    int total = sc[0] + sc[1] + sc[2] + sc[3];
    float acc[4] = {0.f, 0.f, 0.f, 0.f};
    for (int k = 0; k < NPART; ++k) {
#pragma unroll
        for (int e = 0; e < 4; ++e) acc[e] += part[(k * NC + c) * 1024 + tid + 256 * e];
    }
    float inv = 1.f / (float)total;
#pragma unroll
    for (int e = 0; e < 4; ++e) {
        int idx = tid + 256 * e;
        float v = acc[e] * inv;
        P[(idx >> 5) * LDSD + (idx & 31)] = v;
        bary0[c * 1024 + idx] = v;
    }
    __syncthreads();
    if (tid < 64) {
        int half = tid >> 5, lh = tid & 31;
        float z_[32];
        if (half == 0) {
#pragma unroll
            for (int r = 0; r < 32; ++r) {
                int i = r ^ lh;
                z_[r] = 0.5f * (P[i * LDSD + lh] + P[lh * LDSD + i]);
            }
        } else {
#pragma unroll
            for (int r = 0; r < 32; ++r) z_[r] = (r == 0) ? 1.f : 0.f;   // V0 = I col
        }
        rjacobi_split<3>(z_, half, lh);
        float lam = __shfl(z_[0], lh, 64);
        float esq = sqrtf(fmaxf(lam, 0.f));
        float eisq = fast_rsq(fmaxf(lam, 1e-30f));
        if (half == 1) {
#pragma unroll
            for (int r = 0; r < 32; ++r) {
                int i = r ^ lh;
                Q[i * LDSD + lh] = z_[r];            // Q = V
                P[i * LDSD + lh] = z_[r] * esq;      // P = V·diag(sqrt λ)
            }
        }
        mmb_nt_g(P, Q, sqrtm + c * 1024, tid);       // sqrtm = V diag V^T
        if (half == 1) {
#pragma unroll
            for (int r = 0; r < 32; ++r) P[(r ^ lh) * LDSD + lh] = z_[r] * eisq;
        }
        mmb_nt_g(P, Q, invsqrtm + c * 1024, tid);    // invsqrtm = V diag^-1 V^T
    }
}

// tangent: 4 samples per 256-thread block (per-wave P,Q); split-role wave; 1 sweep.
// All LDS is wave-private -> block barriers replaced by sched fences (spill guard).
__global__ void __launch_bounds__(256) k_tangent(const float* X, const int* labels, const float* sqrtm,
                                                 const float* invsqrtm, float* Tbuf) {
    __shared__ __align__(16) float P[4][MAT], Q[4][MAT];   // 34816 B, per-wave
    int tid = threadIdx.x, wv = tid >> 6, t64 = tid & 63;
    int half = t64 >> 5, lh = tid & 31;
    int b = blockIdx.x * 4 + wv;
    int lb = labels[b];
    float* Pw = P[wv];
    float* Qw = Q[wv];
    g2l<64>(X + b * 1024, Pw, t64);
    g2l<64>(invsqrtm + lb * 1024, Qw, t64);
    SCHED_FENCE();
    mmb_nn(Qw, Pw, Pw, t64);                    // P = S·X      (in-place, wave-private)
    SCHED_FENCE();
    mmb_nn(Pw, Qw, Qw, t64);                    // Q = (S·X)·S = M
    SCHED_FENCE();
    g2l<64>(sqrtm + lb * 1024, Pw, t64);        // P = sqrtm
    SCHED_FENCE();
    float z_[32];
    if (half == 0) {
#pragma unroll
        for (int r = 0; r < 32; ++r) {
            int i = r ^ lh;
            z_[r] = 0.5f * (Qw[i * LDSD + lh] + Qw[lh * LDSD + i]);   // symmetrized M
        }
    } else {
#pragma unroll
        for (int r = 0; r < 32; ++r) z_[r] = Pw[(r ^ lh) * LDSD + lh];  // W0 = sqrtm col (skew)
    }
    SCHED_FENCE();
    rjacobi_split<1>(z_, half, lh);
    float lam = __shfl(z_[0], lh, 64);          // wave-local broadcast of half-0 eigenvalue
    float ev = logf(fmaxf(lam, EV_EPS));
    SCHED_FENCE();                               // extraction reads precede stores (in-order wave)
    if (half == 1) {
#pragma unroll
        for (int r = 0; r < 32; ++r) {
            float w = z_[r];
            int i = r ^ lh;
            Qw[i * LDSD + lh] = w;               // Q = W = sqrtm·V
            Pw[i * LDSD + lh] = w * ev;          // P = W·diag(log λ)
        }
    }
    SCHED_FENCE();
    mmb_nt_g(Pw, Qw, Tbuf + b * 1024, t64);      // T = W·diag·W^T
}

// fused: reduce part2 -> meanT (LDS only) -> wave-0 exp-map update -> bary
__global__ void __launch_bounds__(256) k_meanT_update(const float* part2, const int* labels, int B,
                                                      const float* sqrtm, const float* invsqrtm,
                                                      const float* bary0, float* bary) {
    __shared__ __align__(16) float P[MAT], Q[MAT];
    __shared__ int sc[4];
    int c = blockIdx.x, tid = threadIdx.x;
    int cnt = 0;
    for (int b = tid; b < B; b += 256) cnt += (labels[b] == c) ? 1 : 0;
#pragma unroll
    for (int off = 32; off > 0; off >>= 1) cnt += __shfl_down(cnt, off);
    if ((tid & 63) == 0) sc[tid >> 6] = cnt;
    __syncthreads();
    int total = sc[0] + sc[1] + sc[2] + sc[3];
    float acc[4] = {0.f, 0.f, 0.f, 0.f};
    for (int k = 0; k < NPART; ++k) {
#pragma unroll
        for (int e = 0; e < 4; ++e) acc[e] += part2[(k * NC + c) * 1024 + tid + 256 * e];
    }
    float inv = 1.f / (float)total;
#pragma unroll
    for (int e = 0; e < 4; ++e) {
        int idx = tid + 256 * e;
        P[(idx >> 5) * LDSD + (idx & 31)] = acc[e] * inv;   // meanT tile (LDS only)
    }
    __syncthreads();
    if (tid < 64) {
        int half = tid >> 5, lh = tid & 31;
        g2l<64>(invsqrtm + c * 1024, Q, tid);
        mmb_nn(Q, P, P, tid);                    // P = S·meanT
        mmb_nn(P, Q, Q, tid);                    // Q = N
        g2l<64>(sqrtm + c * 1024, P, tid);
        float z_[32];
        if (half == 0) {
#pragma unroll
            for (int r = 0; r < 32; ++r) {
                int i = r ^ lh;
                z_[r] = 0.5f * (Q[i * LDSD + lh] + Q[lh * LDSD + i]);
            }
        } else {
#pragma unroll
            for (int r = 0; r < 32; ++r) z_[r] = P[(r ^ lh) * LDSD + lh];  // W0 = sqrtm col
        }
        rjacobi_split<3>(z_, half, lh);
        float lam = __shfl(z_[0], lh, 64);
        // faithful quirk: clamp eigenvalues to >= 1e-10 BEFORE exp
        float ev = expf(fmaxf(lam, EV_EPS));
        if (half == 1) {
#pragma unroll
            for (int r = 0; r < 32; ++r) {
                float w = z_[r];
                int i = r ^ lh;
                Q[i * LDSD + lh] = w;                // Q = W
                P[i * LDSD + lh] = w * ev;           // P = W·diag(exp λ)
            }
        }
        // newbary tile = P·Q^T per lane; err vs bary0; select; write
        int j2 = (tid & 15) * 2, i0 = (tid >> 4) * 8;
        float2 ac[8];
#pragma unroll
        for (int r = 0; r < 8; ++r) { ac[r].x = 0.f; ac[r].y = 0.f; }
#pragma unroll
        for (int l = 0; l < 32; l += 2) {
            float2 b0 = *(const float2*)&Q[j2 * LDSD + l];
            float2 b1 = *(const float2*)&Q[(j2 + 1) * LDSD + l];
#pragma unroll
            for (int r = 0; r < 8; ++r) {
                float2 a = *(const float2*)&P[(i0 + r) * LDSD + l];
                ac[r].x = fmaf(a.x, b0.x, fmaf(a.y, b0.y, ac[r].x));
                ac[r].y = fmaf(a.x, b1.x, fmaf(a.y, b1.y, ac[r].y));
            }
        }
        float2 bv[8];
        float loc = 0.f;
#pragma unroll
        for (int r = 0; r < 8; ++r) {
            bv[r] = *(const float2*)&bary0[c * 1024 + (i0 + r) * 32 + j2];
            float dx = ac[r].x - bv[r].x, dy = ac[r].y - bv[r].y;
            loc += dx * dx + dy * dy;
        }
#pragma unroll
        for (int off = 32; off > 0; off >>= 1) loc += __shfl_down(loc, off);
        float err2 = __shfl(loc, 0);
        bool keep0 = (err2 < 1e-8f);  // CONV_TOL^2
#pragma unroll
        for (int r = 0; r < 8; ++r) {
            float2 w = keep0 ? bv[r] : ac[r];
            *(float2*)&bary[c * 1024 + (i0 + r) * 32 + j2] = w;
        }
    }
}

// pairdist: barriered Cholesky (256 threads) + barrier-free per-wave class loop
// with sched_barrier(0) fences (round-13 proven form, VGPR 120); 1-sweep Jacobi
__global__ void __launch_bounds__(256) k_pairdist(const float* X, const float* bary, float* D) {
    __shared__ __align__(16) float WA[MAT];        // X -> L -> Wt
    __shared__ __align__(16) float BC[4][MAT];     // per-wave class buffer
    int tid = threadIdx.x, wv = tid >> 6, t64 = tid & 63;
    int half = t64 >> 5, lh = tid & 31;
    int b = blockIdx.x;
    g2l<256>(X + b * 1024, WA, tid);
    __syncthreads();
    if (tid < 32) WA[tid * LDSD + tid] += 1e-3f;   // CHOL_EPS
    __syncthreads();
    // right-looking Cholesky (lower triangle), 256 threads on trailing updates
    for (int k = 0; k < 32; ++k) {
        if (tid == 0) WA[k * LDSD + k] = sqrtf(WA[k * LDSD + k]);
        __syncthreads();
        float invd = fast_rcp(WA[k * LDSD + k]);
        if (tid > k && tid < 32) WA[tid * LDSD + k] *= invd;
        __syncthreads();
        for (int idx = tid; idx < 1024; idx += 256) {
            int i = idx >> 5, j = idx & 31;
            if (i > k && j > k && j <= i) WA[i * LDSD + j] -= WA[i * LDSD + k] * WA[j * LDSD + k];
        }
        __syncthreads();
    }
    // forward substitution: lane j computes column j of W = L^{-1} in registers,
    // then writes row j of Wt = L^{-T} (reads precede writes in wave program order)
    if (tid < 32) {
        const int j = tid;
        float w[32];
#pragma unroll
        for (int i = 0; i < 32; ++i) {
            float acc = (i == j) ? 1.f : 0.f;
#pragma unroll
            for (int k = 0; k < 32; ++k) {
                if (k < i) acc = fmaf(-WA[i * LDSD + k], w[k], acc);
            }
            float val = acc * fast_rcp(WA[i * LDSD + i]);
            w[i] = (i < j) ? 0.f : val;
        }
#pragma unroll
        for (int i = 0; i < 32; ++i) WA[j * LDSD + i] = w[i];   // Wt row j
    }
    __syncthreads();                               // publish Wt to all waves
    // per-wave class loop: no block barriers (Bw wave-private, WA read-only).
    // sched_barrier(0) at phase edges pins scheduling -> no cross-phase load hoist.
    float* Bw = BC[wv];
    float m_[32];
#pragma unroll 1
    for (int h = 0; h < 2; ++h) {
        int c = 2 * wv + h;
        g2l<64>(bary + c * 1024, Bw, t64);
        SCHED_FENCE();
        mmb_nn(WA, Bw, Bw, t64);              // Y = Wt·bary  (in-place, wave-private)
        SCHED_FENCE();
        mmb_nn(Bw, WA, Bw, t64);              // M = Y·Wt     (in-place, wave-private)
        SCHED_FENCE();
        if (half == h) {
#pragma unroll
            for (int r = 0; r < 32; ++r) {
                int i = r ^ lh;
                int hi = i > lh ? i : lh, lo = i > lh ? lh : i;  // eigvalsh UPLO='L'
                m_[r] = Bw[hi * LDSD + lo];
            }
        }
        SCHED_FENCE();
    }
    rjacobi_fixed(m_, 1);
    float lg = logf(fmaxf(m_[0], EV_EPS));
    float d2 = lg * lg;
#pragma unroll
    for (int off = 16; off > 0; off >>= 1) d2 += __shfl_xor(d2, off, 32);
    if (lh == 0) D[b * NC + 2 * wv + half] = sqrtf(d2);
}

__global__ void k_loss(const float* out, const int* labels, const float* D, int B, float* res) {
    __shared__ float sI[256], sD[256], sC[256];
    int tid = threadIdx.x;
    float aI = 0.f, aD = 0.f, aC = 0.f;
    for (int b = tid; b < B; b += 256) {
        int lb = labels[b];
        const float* ob = out + b * NC;
        float m = ob[0];
#pragma unroll
        for (int j = 1; j < NC; ++j) m = fmaxf(m, ob[j]);
        float se = 0.f;
#pragma unroll
        for (int j = 0; j < NC; ++j) se += expf(ob[j] - m);
        aC += m + logf(se) - ob[lb];
        const float* db = D + b * NC;
        float s = 0.f;
#pragma unroll
        for (int j = 0; j < NC; ++j) s += db[j];
        aI += db[lb];
        aD += s - db[lb];
    }
    sI[tid] = aI; sD[tid] = aD; sC[tid] = aC;
    __syncthreads();
    for (int off = 128; off > 0; off >>= 1) {
        if (tid < off) { sI[tid] += sI[tid + off]; sD[tid] += sD[tid + off]; sC[tid] += sC[tid + off]; }
        __syncthreads();
    }
    if (tid == 0) {
        float intra = 0.001f * sI[0] / (float)B;
        float disp = sD[0] / (float)(B * (NC - 1));
        float ce = sC[0] / (float)B;
        res[0] = intra - 0.001f * disp + ce;
    }
}

extern "C" void kernel_launch(void* const* d_in, const int* in_sizes, int n_in,
                              void* d_out, int out_size, void* d_ws, size_t ws_size,
                              hipStream_t stream) {
    const float* X = (const float*)d_in[0];
    const float* out = (const float*)d_in[1];
    const int* labels = (const int*)d_in[2];
    int B = in_sizes[2];

    float* ws = (float*)d_ws;
    float* bary0    = ws;                 // 8192
    float* sqrtm    = ws + 8192;          // 8192
    float* invsqrtm = ws + 16384;         // 8192
    float* bary     = ws + 32768;         // 8192
    float* D        = ws + 40960;         // B*8 = 16384
    float* big      = ws + 65536;         // B*1024 floats (partials, then T)
    float* part2    = ws + 65536 + (size_t)B * 1024;  // NPART*NC*1024 floats

    k_accum_part<<<NPART, 256, 0, stream>>>(X, labels, B, big);
    k_bary0_eig<<<NC, 256, 0, stream>>>(big, labels, B, bary0, sqrtm, invsqrtm);
    k_tangent<<<B / 4, 256, 0, stream>>>(X, labels, sqrtm, invsqrtm, big);
    k_accum_part<<<NPART, 256, 0, stream>>>(big, labels, B, part2);
    k_meanT_update<<<NC, 256, 0, stream>>>(part2, labels, B, sqrtm, invsqrtm, bary0, bary);
    k_pairdist<<<B, 256, 0, stream>>>(X, bary, D);
    k_loss<<<1, 256, 0, stream>>>(out, labels, D, B, (float*)d_out);
}

// Round 16
// 796.581 us; speedup vs baseline: 2.9407x; 1.0200x over previous
//
#include <hip/hip_runtime.h>
#include <math.h>

#define NC 8
#define NDIM 32
#define LDSD 34            // stride 34: rows 8B-aligned (float2); col access 2-way bank alias (free)
#define MAT (NDIM * LDSD)  // 1088 floats per LDS matrix
#define EV_EPS 1e-10f
#define NPART 64

#if __has_builtin(__builtin_amdgcn_rcpf)
__device__ inline float fast_rcp(float x) { return __builtin_amdgcn_rcpf(x); }
#else
__device__ inline float fast_rcp(float x) { return 1.f / x; }
#endif
#if __has_builtin(__builtin_amdgcn_rsqf)
__device__ inline float fast_rsq(float x) { return __builtin_amdgcn_rsqf(x); }
#else
__device__ inline float fast_rsq(float x) { return 1.f / sqrtf(x); }
#endif

#define SCHED_FENCE() __builtin_amdgcn_sched_barrier(0)

// ---------- 32x32 LDS helpers ----------
template <int NT>
__device__ inline void g2l(const float* g, float* l, int t) {
    for (int idx2 = t; idx2 < 512; idx2 += NT) {
        int i = idx2 >> 4, jp = idx2 & 15;
        *(float2*)&l[i * LDSD + 2 * jp] = *(const float2*)&g[i * 32 + 2 * jp];
    }
}
// g2l with CHOL_EPS added to the diagonal during staging (saves a barrier+pass)
template <int NT>
__device__ inline void g2l_eps(const float* g, float* l, int t) {
    for (int idx2 = t; idx2 < 512; idx2 += NT) {
        int i = idx2 >> 4, jp = idx2 & 15;
        float2 v = *(const float2*)&g[i * 32 + 2 * jp];
        if (i == 2 * jp) v.x += 1e-3f;
        if (i == 2 * jp + 1) v.y += 1e-3f;
        *(float2*)&l[i * LDSD + 2 * jp] = v;
    }
}

// ---------- register-tiled LDS matmuls (one wave; 8-row x 2-col tile/lane; t = 0..63) ----------
// C = A * B.  Wave-private safe for ANY aliasing (C==A or C==B): all read
// instructions precede all stores in the wave's in-order instruction stream.
__device__ inline void mmb_nn(const float* A, const float* B, float* C, int t) {
    int j2 = (t & 15) * 2;
    int i0 = (t >> 4) * 8;
    float2 ac[8];
#pragma unroll
    for (int r = 0; r < 8; ++r) { ac[r].x = 0.f; ac[r].y = 0.f; }
#pragma unroll
    for (int k = 0; k < 32; k += 2) {
        float2 b0 = *(const float2*)&B[k * LDSD + j2];
        float2 b1 = *(const float2*)&B[(k + 1) * LDSD + j2];
#pragma unroll
        for (int r = 0; r < 8; ++r) {
            float2 a = *(const float2*)&A[(i0 + r) * LDSD + k];
            ac[r].x = fmaf(a.x, b0.x, fmaf(a.y, b1.x, ac[r].x));
            ac[r].y = fmaf(a.x, b0.y, fmaf(a.y, b1.y, ac[r].y));
        }
    }
#pragma unroll
    for (int r = 0; r < 8; ++r) *(float2*)&C[(i0 + r) * LDSD + j2] = ac[r];
}
// gC(global, stride 32) = A * B^T
__device__ inline void mmb_nt_g(const float* A, const float* B, float* gC, int t) {
    int j2 = (t & 15) * 2;
    int i0 = (t >> 4) * 8;
    float2 ac[8];
#pragma unroll
    for (int r = 0; r < 8; ++r) { ac[r].x = 0.f; ac[r].y = 0.f; }
#pragma unroll
    for (int l = 0; l < 32; l += 2) {
        float2 b0 = *(const float2*)&B[j2 * LDSD + l];
        float2 b1 = *(const float2*)&B[(j2 + 1) * LDSD + l];
#pragma unroll
        for (int r = 0; r < 8; ++r) {
            float2 a = *(const float2*)&A[(i0 + r) * LDSD + l];
            ac[r].x = fmaf(a.x, b0.x, fmaf(a.y, b0.y, ac[r].x));
            ac[r].y = fmaf(a.x, b1.x, fmaf(a.y, b1.y, ac[r].y));
        }
    }
#pragma unroll
    for (int r = 0; r < 8; ++r) *(float2*)&gC[(i0 + r) * 32 + j2] = ac[r];
}

// ---------- register-resident XOR-ordered Jacobi, eigenvalues only, fixed sweeps ----------
// Lane lh holds column lh skewed: m_[r] = M[r^lh][lh]; diag = m_[0].
__device__ inline void rjacobi_fixed(float* m_, int nsweep) {
    for (int sweep = 0; sweep < nsweep; ++sweep) {
#pragma unroll
        for (int mm = 1; mm < 32; ++mm) {
            float app = m_[0];
            float aqq = __shfl_xor(app, mm, 32);
            float apq = m_[mm];
            float apqc = __builtin_copysignf(fmaxf(fabsf(apq), 1e-36f), apq);
            float tau = (aqq - app) * 0.5f * fast_rcp(apqc);
            float den = fabsf(tau) + sqrtf(fmaf(tau, tau, 1.f));
            float t = __builtin_copysignf(fast_rcp(den), tau);
            t = (fabsf(apq) > 1e-36f) ? t : 0.f;
            float cc = fast_rsq(fmaf(t, t, 1.f));
            float ss = t * cc;
#pragma unroll
            for (int r = 0; r < 32; ++r) {
                if (r < (r ^ mm)) {
                    const int r2 = r ^ mm;
                    float ti = __shfl_xor(t, r, 32);
                    float ci = fast_rsq(fmaf(ti, ti, 1.f));
                    float si = ti * ci;
                    float x = m_[r], y = m_[r2];
                    m_[r]  = ci * x - si * y;
                    m_[r2] = ci * y + si * x;
                }
            }
            float o[32];
#pragma unroll
            for (int u = 0; u < 32; ++u) o[u] = __shfl_xor(m_[u ^ mm], mm, 32);
#pragma unroll
            for (int u = 0; u < 32; ++u) m_[u] = fmaf(cc, m_[u], -ss * o[u]);
        }
    }
}

// ---------- split-role register Jacobi: half 0 solves M, half 1 accumulates W·V ----------
template <int NSWEEP>
__device__ inline void rjacobi_split(float* z_, int half, int lh) {
    for (int sweep = 0; sweep < NSWEEP; ++sweep) {
#pragma unroll
        for (int mm = 1; mm < 32; ++mm) {
            float app = z_[0];
            float aqq = __shfl_xor(app, mm, 32);
            float apq = z_[mm];
            float apqc = __builtin_copysignf(fmaxf(fabsf(apq), 1e-36f), apq);
            float tau = (aqq - app) * 0.5f * fast_rcp(apqc);
            float den = fabsf(tau) + sqrtf(fmaf(tau, tau, 1.f));
            float t = __builtin_copysignf(fast_rcp(den), tau);
            t = (fabsf(apq) > 1e-36f) ? t : 0.f;
            t = __shfl(t, lh, 64);               // half 1 inherits half 0's t (wave-local)
            float cc = fast_rsq(fmaf(t, t, 1.f));
            float ss = t * cc;
            if (half == 0) {                     // row rotations on M only (t-refetch)
#pragma unroll
                for (int r = 0; r < 32; ++r) {
                    if (r < (r ^ mm)) {
                        const int r2 = r ^ mm;
                        float ti = __shfl_xor(t, r, 32);
                        float ci = fast_rsq(fmaf(ti, ti, 1.f));
                        float si = ti * ci;
                        float x = z_[r], y = z_[r2];
                        z_[r]  = ci * x - si * y;
                        z_[r2] = ci * y + si * x;
                    }
                }
            }
            float o[32];
#pragma unroll
            for (int u = 0; u < 32; ++u) o[u] = __shfl_xor(z_[u ^ mm], mm, 32);
#pragma unroll
            for (int u = 0; u < 32; ++u) z_[u] = fmaf(cc, z_[u], -ss * o[u]);
        }
    }
}

// ---------- kernels ----------
__global__ void __launch_bounds__(256) k_accum_part(const float* src, const int* labels, int B, float* part) {
    int blk = blockIdx.x, tid = threadIdx.x;
    int chunk = (B + NPART - 1) / NPART;
    int b0 = blk * chunk, b1 = b0 + chunk < B ? b0 + chunk : B;
    float acc[NC][4];
#pragma unroll
    for (int c = 0; c < NC; ++c)
#pragma unroll
        for (int e = 0; e < 4; ++e) acc[c][e] = 0.f;
    for (int b = b0; b < b1; ++b) {
        int lb = labels[b];
        float x[4];
#pragma unroll
        for (int e = 0; e < 4; ++e) x[e] = src[b * 1024 + tid + 256 * e];
#pragma unroll
        for (int c = 0; c < NC; ++c) {
            if (lb == c) {
#pragma unroll
                for (int e = 0; e < 4; ++e) acc[c][e] += x[e];
            }
        }
    }
#pragma unroll
    for (int c = 0; c < NC; ++c)
#pragma unroll
        for (int e = 0; e < 4; ++e) part[(blk * NC + c) * 1024 + tid + 256 * e] = acc[c][e];
}

// fused: reduce partials -> bary0 (global + LDS tile) -> wave-0 eigen -> sqrtm/invsqrtm
__global__ void __launch_bounds__(256) k_bary0_eig(const float* part, const int* labels, int B,
                                                   float* bary0, float* sqrtm, float* invsqrtm) {
    __shared__ __align__(16) float P[MAT], Q[MAT];
    __shared__ int sc[4];
    int c = blockIdx.x, tid = threadIdx.x;
    int cnt = 0;
    for (int b = tid; b < B; b += 256) cnt += (labels[b] == c) ? 1 : 0;
#pragma unroll
    for (int off = 32; off > 0; off >>= 1) cnt += __shfl_down(cnt, off);
    if ((tid & 63) == 0) sc[tid >> 6] = cnt;
    __syncthreads();
    int total = sc[0] + sc[1] + sc[2] + sc[3];
    float acc[4] = {0.f, 0.f, 0.f, 0.f};
    for (int k = 0; k < NPART; ++k) {
#pragma unroll
        for (int e = 0; e < 4; ++e) acc[e] += part[(k * NC + c) * 1024 + tid + 256 * e];
    }
    float inv = 1.f / (float)total;
#pragma unroll
    for (int e = 0; e < 4; ++e) {
        int idx = tid + 256 * e;
        float v = acc[e] * inv;
        P[(idx >> 5) * LDSD + (idx & 31)] = v;
        bary0[c * 1024 + idx] = v;
    }
    __syncthreads();
    if (tid < 64) {
        int half = tid >> 5, lh = tid & 31;
        float z_[32];
        if (half == 0) {
#pragma unroll
            for (int r = 0; r < 32; ++r) {
                int i = r ^ lh;
                z_[r] = 0.5f * (P[i * LDSD + lh] + P[lh * LDSD + i]);
            }
        } else {
#pragma unroll
            for (int r = 0; r < 32; ++r) z_[r] = (r == 0) ? 1.f : 0.f;   // V0 = I col
        }
        rjacobi_split<3>(z_, half, lh);
        float lam = __shfl(z_[0], lh, 64);
        float esq = sqrtf(fmaxf(lam, 0.f));
        float eisq = fast_rsq(fmaxf(lam, 1e-30f));
        if (half == 1) {
#pragma unroll
            for (int r = 0; r < 32; ++r) {
                int i = r ^ lh;
                Q[i * LDSD + lh] = z_[r];            // Q = V
                P[i * LDSD + lh] = z_[r] * esq;      // P = V·diag(sqrt λ)
            }
        }
        mmb_nt_g(P, Q, sqrtm + c * 1024, tid);       // sqrtm = V diag V^T
        if (half == 1) {
#pragma unroll
            for (int r = 0; r < 32; ++r) P[(r ^ lh) * LDSD + lh] = z_[r] * eisq;
        }
        mmb_nt_g(P, Q, invsqrtm + c * 1024, tid);    // invsqrtm = V diag^-1 V^T
    }
}

// tangent: 4 samples per 256-thread block (per-wave P,Q); split-role wave; 1 sweep.
// All LDS is wave-private -> block barriers replaced by sched fences (spill guard).
__global__ void __launch_bounds__(256) k_tangent(const float* X, const int* labels, const float* sqrtm,
                                                 const float* invsqrtm, float* Tbuf) {
    __shared__ __align__(16) float P[4][MAT], Q[4][MAT];   // 34816 B, per-wave
    int tid = threadIdx.x, wv = tid >> 6, t64 = tid & 63;
    int half = t64 >> 5, lh = tid & 31;
    int b = blockIdx.x * 4 + wv;
    int lb = labels[b];
    float* Pw = P[wv];
    float* Qw = Q[wv];
    g2l<64>(X + b * 1024, Pw, t64);
    g2l<64>(invsqrtm + lb * 1024, Qw, t64);
    SCHED_FENCE();
    mmb_nn(Qw, Pw, Pw, t64);                    // P = S·X      (in-place, wave-private)
    SCHED_FENCE();
    mmb_nn(Pw, Qw, Qw, t64);                    // Q = (S·X)·S = M
    SCHED_FENCE();
    g2l<64>(sqrtm + lb * 1024, Pw, t64);        // P = sqrtm
    SCHED_FENCE();
    float z_[32];
    if (half == 0) {
#pragma unroll
        for (int r = 0; r < 32; ++r) {
            int i = r ^ lh;
            z_[r] = 0.5f * (Qw[i * LDSD + lh] + Qw[lh * LDSD + i]);   // symmetrized M
        }
    } else {
#pragma unroll
        for (int r = 0; r < 32; ++r) z_[r] = Pw[(r ^ lh) * LDSD + lh];  // W0 = sqrtm col (skew)
    }
    SCHED_FENCE();
    rjacobi_split<1>(z_, half, lh);
    float lam = __shfl(z_[0], lh, 64);          // wave-local broadcast of half-0 eigenvalue
    float ev = logf(fmaxf(lam, EV_EPS));
    SCHED_FENCE();                               // extraction reads precede stores (in-order wave)
    if (half == 1) {
#pragma unroll
        for (int r = 0; r < 32; ++r) {
            float w = z_[r];
            int i = r ^ lh;
            Qw[i * LDSD + lh] = w;               // Q = W = sqrtm·V
            Pw[i * LDSD + lh] = w * ev;          // P = W·diag(log λ)
        }
    }
    SCHED_FENCE();
    mmb_nt_g(Pw, Qw, Tbuf + b * 1024, t64);      // T = W·diag·W^T
}

// fused: reduce part2 -> meanT (LDS only) -> wave-0 exp-map update -> bary
__global__ void __launch_bounds__(256) k_meanT_update(const float* part2, const int* labels, int B,
                                                      const float* sqrtm, const float* invsqrtm,
                                                      const float* bary0, float* bary) {
    __shared__ __align__(16) float P[MAT], Q[MAT];
    __shared__ int sc[4];
    int c = blockIdx.x, tid = threadIdx.x;
    int cnt = 0;
    for (int b = tid; b < B; b += 256) cnt += (labels[b] == c) ? 1 : 0;
#pragma unroll
    for (int off = 32; off > 0; off >>= 1) cnt += __shfl_down(cnt, off);
    if ((tid & 63) == 0) sc[tid >> 6] = cnt;
    __syncthreads();
    int total = sc[0] + sc[1] + sc[2] + sc[3];
    float acc[4] = {0.f, 0.f, 0.f, 0.f};
    for (int k = 0; k < NPART; ++k) {
#pragma unroll
        for (int e = 0; e < 4; ++e) acc[e] += part2[(k * NC + c) * 1024 + tid + 256 * e];
    }
    float inv = 1.f / (float)total;
#pragma unroll
    for (int e = 0; e < 4; ++e) {
        int idx = tid + 256 * e;
        P[(idx >> 5) * LDSD + (idx & 31)] = acc[e] * inv;   // meanT tile (LDS only)
    }
    __syncthreads();
    if (tid < 64) {
        int half = tid >> 5, lh = tid & 31;
        g2l<64>(invsqrtm + c * 1024, Q, tid);
        mmb_nn(Q, P, P, tid);                    // P = S·meanT
        mmb_nn(P, Q, Q, tid);                    // Q = N
        g2l<64>(sqrtm + c * 1024, P, tid);
        float z_[32];
        if (half == 0) {
#pragma unroll
            for (int r = 0; r < 32; ++r) {
                int i = r ^ lh;
                z_[r] = 0.5f * (Q[i * LDSD + lh] + Q[lh * LDSD + i]);
            }
        } else {
#pragma unroll
            for (int r = 0; r < 32; ++r) z_[r] = P[(r ^ lh) * LDSD + lh];  // W0 = sqrtm col
        }
        rjacobi_split<3>(z_, half, lh);
        float lam = __shfl(z_[0], lh, 64);
        // faithful quirk: clamp eigenvalues to >= 1e-10 BEFORE exp
        float ev = expf(fmaxf(lam, EV_EPS));
        if (half == 1) {
#pragma unroll
            for (int r = 0; r < 32; ++r) {
                float w = z_[r];
                int i = r ^ lh;
                Q[i * LDSD + lh] = w;                // Q = W
                P[i * LDSD + lh] = w * ev;           // P = W·diag(exp λ)
            }
        }
        // newbary tile = P·Q^T per lane; err vs bary0; select; write
        int j2 = (tid & 15) * 2, i0 = (tid >> 4) * 8;
        float2 ac[8];
#pragma unroll
        for (int r = 0; r < 8; ++r) { ac[r].x = 0.f; ac[r].y = 0.f; }
#pragma unroll
        for (int l = 0; l < 32; l += 2) {
            float2 b0 = *(const float2*)&Q[j2 * LDSD + l];
            float2 b1 = *(const float2*)&Q[(j2 + 1) * LDSD + l];
#pragma unroll
            for (int r = 0; r < 8; ++r) {
                float2 a = *(const float2*)&P[(i0 + r) * LDSD + l];
                ac[r].x = fmaf(a.x, b0.x, fmaf(a.y, b0.y, ac[r].x));
                ac[r].y = fmaf(a.x, b1.x, fmaf(a.y, b1.y, ac[r].y));
            }
        }
        float2 bv[8];
        float loc = 0.f;
#pragma unroll
        for (int r = 0; r < 8; ++r) {
            bv[r] = *(const float2*)&bary0[c * 1024 + (i0 + r) * 32 + j2];
            float dx = ac[r].x - bv[r].x, dy = ac[r].y - bv[r].y;
            loc += dx * dx + dy * dy;
        }
#pragma unroll
        for (int off = 32; off > 0; off >>= 1) loc += __shfl_down(loc, off);
        float err2 = __shfl(loc, 0);
        bool keep0 = (err2 < 1e-8f);  // CONV_TOL^2
#pragma unroll
        for (int r = 0; r < 8; ++r) {
            float2 w = keep0 ? bv[r] : ac[r];
            *(float2*)&bary[c * 1024 + (i0 + r) * 32 + j2] = w;
        }
    }
}

// pairdist: 2-barrier-per-iter Cholesky (redundant sqrt in registers) +
// barrier-free per-wave class loop with sched fences; 1-sweep Jacobi
__global__ void __launch_bounds__(256) k_pairdist(const float* X, const float* bary, float* D) {
    __shared__ __align__(16) float WA[MAT];        // X -> L -> Wt
    __shared__ __align__(16) float BC[4][MAT];     // per-wave class buffer
    int tid = threadIdx.x, wv = tid >> 6, t64 = tid & 63;
    int half = t64 >> 5, lh = tid & 31;
    int b = blockIdx.x;
    g2l_eps<256>(X + b * 1024, WA, tid);           // stage X with CHOL_EPS on diag
    __syncthreads();
    // right-looking Cholesky (lower triangle), 2 barriers per iteration:
    // all threads redundantly compute d=sqrt(diag), invd=1/d from the PRE-sqrt value.
    for (int k = 0; k < 32; ++k) {
        float raw = WA[k * LDSD + k];
        float d = sqrtf(raw);
        float invd = fast_rcp(d);
        if (tid == 0) WA[k * LDSD + k] = d;
        if (tid > k && tid < 32) WA[tid * LDSD + k] *= invd;
        __syncthreads();                           // scaled col k (and diag) visible
        for (int idx = tid; idx < 1024; idx += 256) {
            int i = idx >> 5, j = idx & 31;
            if (i > k && j > k && j <= i) WA[i * LDSD + j] -= WA[i * LDSD + k] * WA[j * LDSD + k];
        }
        __syncthreads();                           // trailing update done
    }
    // forward substitution: lane j computes column j of W = L^{-1} in registers,
    // then writes row j of Wt = L^{-T} (reads precede writes in wave program order)
    if (tid < 32) {
        const int j = tid;
        float w[32];
#pragma unroll
        for (int i = 0; i < 32; ++i) {
            float acc = (i == j) ? 1.f : 0.f;
#pragma unroll
            for (int k = 0; k < 32; ++k) {
                if (k < i) acc = fmaf(-WA[i * LDSD + k], w[k], acc);
            }
            float val = acc * fast_rcp(WA[i * LDSD + i]);
            w[i] = (i < j) ? 0.f : val;
        }
#pragma unroll
        for (int i = 0; i < 32; ++i) WA[j * LDSD + i] = w[i];   // Wt row j
    }
    __syncthreads();                               // publish Wt to all waves
    // per-wave class loop: no block barriers (Bw wave-private, WA read-only).
    // sched_barrier(0) at phase edges pins scheduling -> no cross-phase load hoist.
    float* Bw = BC[wv];
    float m_[32];
#pragma unroll 1
    for (int h = 0; h < 2; ++h) {
        int c = 2 * wv + h;
        g2l<64>(bary + c * 1024, Bw, t64);
        SCHED_FENCE();
        mmb_nn(WA, Bw, Bw, t64);              // Y = Wt·bary  (in-place, wave-private)
        SCHED_FENCE();
        mmb_nn(Bw, WA, Bw, t64);              // M = Y·Wt     (in-place, wave-private)
        SCHED_FENCE();
        if (half == h) {
#pragma unroll
            for (int r = 0; r < 32; ++r) {
                int i = r ^ lh;
                int hi = i > lh ? i : lh, lo = i > lh ? lh : i;  // eigvalsh UPLO='L'
                m_[r] = Bw[hi * LDSD + lo];
            }
        }
        SCHED_FENCE();
    }
    rjacobi_fixed(m_, 1);
    float lg = logf(fmaxf(m_[0], EV_EPS));
    float d2 = lg * lg;
#pragma unroll
    for (int off = 16; off > 0; off >>= 1) d2 += __shfl_xor(d2, off, 32);
    if (lh == 0) D[b * NC + 2 * wv + half] = sqrtf(d2);
}

__global__ void k_loss(const float* out, const int* labels, const float* D, int B, float* res) {
    __shared__ float sI[256], sD[256], sC[256];
    int tid = threadIdx.x;
    float aI = 0.f, aD = 0.f, aC = 0.f;
    for (int b = tid; b < B; b += 256) {
        int lb = labels[b];
        const float* ob = out + b * NC;
        float m = ob[0];
#pragma unroll
        for (int j = 1; j < NC; ++j) m = fmaxf(m, ob[j]);
        float se = 0.f;
#pragma unroll
        for (int j = 0; j < NC; ++j) se += expf(ob[j] - m);
        aC += m + logf(se) - ob[lb];
        const float* db = D + b * NC;
        float s = 0.f;
#pragma unroll
        for (int j = 0; j < NC; ++j) s += db[j];
        aI += db[lb];
        aD += s - db[lb];
    }
    sI[tid] = aI; sD[tid] = aD; sC[tid] = aC;
    __syncthreads();
    for (int off = 128; off > 0; off >>= 1) {
        if (tid < off) { sI[tid] += sI[tid + off]; sD[tid] += sD[tid + off]; sC[tid] += sC[tid + off]; }
        __syncthreads();
    }
    if (tid == 0) {
        float intra = 0.001f * sI[0] / (float)B;
        float disp = sD[0] / (float)(B * (NC - 1));
        float ce = sC[0] / (float)B;
        res[0] = intra - 0.001f * disp + ce;
    }
}

extern "C" void kernel_launch(void* const* d_in, const int* in_sizes, int n_in,
                              void* d_out, int out_size, void* d_ws, size_t ws_size,
                              hipStream_t stream) {
    const float* X = (const float*)d_in[0];
    const float* out = (const float*)d_in[1];
    const int* labels = (const int*)d_in[2];
    int B = in_sizes[2];

    float* ws = (float*)d_ws;
    float* bary0    = ws;                 // 8192
    float* sqrtm    = ws + 8192;          // 8192
    float* invsqrtm = ws + 16384;         // 8192
    float* bary     = ws + 32768;         // 8192
    float* D        = ws + 40960;         // B*8 = 16384
    float* big      = ws + 65536;         // B*1024 floats (partials, then T)
    float* part2    = ws + 65536 + (size_t)B * 1024;  // NPART*NC*1024 floats

    k_accum_part<<<NPART, 256, 0, stream>>>(X, labels, B, big);
    k_bary0_eig<<<NC, 256, 0, stream>>>(big, labels, B, bary0, sqrtm, invsqrtm);
    k_tangent<<<B / 4, 256, 0, stream>>>(X, labels, sqrtm, invsqrtm, big);
    k_accum_part<<<NPART, 256, 0, stream>>>(big, labels, B, part2);
    k_meanT_update<<<NC, 256, 0, stream>>>(part2, labels, B, sqrtm, invsqrtm, bary0, bary);
    k_pairdist<<<B, 256, 0, stream>>>(X, bary, D);
    k_loss<<<1, 256, 0, stream>>>(out, labels, D, B, (float*)d_out);
}